// Round 6
// baseline (1878.905 us; speedup 1.0000x reference)
//
#include <hip/hip_runtime.h>
#include <hip/hip_fp16.h>

#define N_NODES_C 1000000
#define N_ELEMS_C 4000000
#define N_ENDP_C  (2 * N_ELEMS_C)
#define TILE 1024
#define N_TILES ((N_NODES_C + TILE - 1) / TILE)   // 977
#define HIST_EPT 8
#define MAIN_EPT 4
#define NPB 512                                    // nodes per block in node_rot
#define N_NBLOCKS ((N_NODES_C + NPB - 1) / NPB)    // 1954

struct Scalars {
    double S_kin;
    double L_sum;
    double S_Fext;
    double S_force;
    double S_mom;
    double S_neu;
    unsigned long long n_fd;
    unsigned long long n_fr;
    unsigned long long n_pin;
    int q_max_bits;
    int L_max_bits;
};

__device__ __forceinline__ double waveSumD(double v) {
    for (int off = 32; off > 0; off >>= 1) v += __shfl_down(v, off, 64);
    return v;
}
__device__ __forceinline__ float waveMaxF(float v) {
    for (int off = 32; off > 0; off >>= 1) v = fmaxf(v, __shfl_down(v, off, 64));
    return v;
}
__device__ __forceinline__ int waveSumI(int v) {
    for (int off = 32; off > 0; off >>= 1) v += __shfl_down(v, off, 64);
    return v;
}
__device__ __forceinline__ unsigned packH2(float a, float b) {
    return (unsigned)__half_as_ushort(__float2half(a)) |
           ((unsigned)__half_as_ushort(__float2half(b)) << 16);
}
__device__ __forceinline__ float lowH(unsigned u)  { return __half2float(__ushort_as_half((unsigned short)(u & 0xFFFFu))); }
__device__ __forceinline__ float highH(unsigned u) { return __half2float(__ushort_as_half((unsigned short)(u >> 16))); }
// embed nb low bits into float mantissa (rel err <= 2^-(23-nb), harmless)
__device__ __forceinline__ float embedBits(float f, unsigned bits, unsigned nb) {
    unsigned u = __float_as_uint(f);
    u = (u & ~((1u << nb) - 1u)) | bits;
    return __uint_as_float(u);
}

// ============ node-data pack: 10 floats tight (40B) per node ============
// layout: ux0 ux1 | ux2 uz0 | uz1 uz2 | gp0 gp1 | gp2 phi
__global__ __launch_bounds__(256) void pack_nodes10(
    const float* __restrict__ phi,
    const float* __restrict__ grad_ux,
    const float* __restrict__ grad_uz,
    const float* __restrict__ grad_phi,
    float2* __restrict__ pack)          // 5 float2 per node
{
    int n = blockIdx.x * blockDim.x + threadIdx.x;
    if (n >= N_NODES_C) return;
    size_t n3 = 3 * (size_t)n;
    float ux0 = grad_ux[n3 + 0], ux1 = grad_ux[n3 + 1], ux2 = grad_ux[n3 + 2];
    float uz0 = grad_uz[n3 + 0], uz1 = grad_uz[n3 + 1], uz2 = grad_uz[n3 + 2];
    float gp0 = grad_phi[n3 + 0], gp1 = grad_phi[n3 + 1], gp2 = grad_phi[n3 + 2];
    float ph  = phi[n];
    float2* P = pack + (size_t)n * 5;
    P[0] = make_float2(ux0, ux1);
    P[1] = make_float2(ux2, uz0);
    P[2] = make_float2(uz1, uz2);
    P[3] = make_float2(gp0, gp1);
    P[4] = make_float2(gp2, ph);
}

// ============ hist + RANK: single atomic pass (returning atomicAdd) ============
__global__ __launch_bounds__(256) void hist_rank(
    const int* __restrict__ conn,
    const float* __restrict__ elem_len,
    const float* __restrict__ load,
    int* __restrict__ counts,
    uchar2* __restrict__ rank2,
    Scalars* __restrict__ sc)
{
    int base = blockIdx.x * (256 * HIST_EPT) + threadIdx.x;
    double lsum = 0.0;
    float qm = 0.0f, lm = 0.0f;

    int2 ij[HIST_EPT];
    int ri[HIST_EPT], rj[HIST_EPT];
    bool valid[HIST_EPT];
#pragma unroll
    for (int k = 0; k < HIST_EPT; ++k) {
        int e = base + k * 256;
        valid[k] = (e < N_ELEMS_C);
        if (valid[k]) ij[k] = ((const int2*)conn)[e];
    }
    // 16 independent returning atomics in flight
#pragma unroll
    for (int k = 0; k < HIST_EPT; ++k) {
        if (valid[k]) {
            ri[k] = atomicAdd(&counts[ij[k].x], 1);
            rj[k] = atomicAdd(&counts[ij[k].y], 1);
        }
    }
#pragma unroll
    for (int k = 0; k < HIST_EPT; ++k) {
        int e = base + k * 256;
        if (valid[k]) {
            rank2[e] = make_uchar2((unsigned char)min(ri[k], 255),
                                   (unsigned char)min(rj[k], 255));
        }
    }
#pragma unroll
    for (int k = 0; k < HIST_EPT; ++k) {
        int e = base + k * 256;
        if (valid[k]) {
            float L = elem_len[e];
            float q0 = load[3 * (size_t)e + 0];
            float q1 = load[3 * (size_t)e + 1];
            float q2 = load[3 * (size_t)e + 2];
            lsum += (double)L;
            lm = fmaxf(lm, L);
            qm = fmaxf(qm, fmaxf(fmaxf(fabsf(q0), fabsf(q1)), fabsf(q2)));
        }
    }

    lsum = waveSumD(lsum);
    qm = waveMaxF(qm);
    lm = waveMaxF(lm);
    if ((threadIdx.x & 63) == 0) {
        atomicAdd(&sc->L_sum, lsum);
        atomicMax(&sc->q_max_bits, __float_as_int(qm));
        atomicMax(&sc->L_max_bits, __float_as_int(lm));
    }
}

// ============ scan kernels (verified) ============

__global__ __launch_bounds__(256) void tile_sum(
    const int* __restrict__ counts, int* __restrict__ tileSums)
{
    int tile = blockIdx.x;
    int base = tile * TILE;
    int s = 0;
    for (int k = threadIdx.x; k < TILE; k += 256) {
        int idx = base + k;
        s += (idx < N_NODES_C) ? counts[idx] : 0;
    }
    s = waveSumI(s);
    __shared__ int sh[4];
    if ((threadIdx.x & 63) == 0) sh[threadIdx.x >> 6] = s;
    __syncthreads();
    if (threadIdx.x == 0) tileSums[tile] = sh[0] + sh[1] + sh[2] + sh[3];
}

__global__ __launch_bounds__(1024) void scan_tiles(int* __restrict__ tileSums)
{
    __shared__ int sh[1024];
    int t = threadIdx.x;
    int v = (t < N_TILES) ? tileSums[t] : 0;
    sh[t] = v;
    __syncthreads();
    for (int s = 1; s < 1024; s <<= 1) {
        int a = (t >= s) ? sh[t - s] : 0;
        __syncthreads();
        sh[t] += a;
        __syncthreads();
    }
    if (t < N_TILES) tileSums[t] = sh[t] - v;   // exclusive over tiles
}

// EXCLUSIVE scan -> offsets (start offsets)
__global__ __launch_bounds__(256) void scan_within(
    const int* __restrict__ counts, const int* __restrict__ tileSums,
    int* __restrict__ offsets)
{
    int tile = blockIdx.x;
    int base = tile * TILE;
    int t = threadIdx.x;
    int i0 = base + t * 4;
    int c0 = (i0 + 0 < N_NODES_C) ? counts[i0 + 0] : 0;
    int c1 = (i0 + 1 < N_NODES_C) ? counts[i0 + 1] : 0;
    int c2 = (i0 + 2 < N_NODES_C) ? counts[i0 + 2] : 0;
    int c3 = (i0 + 3 < N_NODES_C) ? counts[i0 + 3] : 0;
    int tsum = c0 + c1 + c2 + c3;
    __shared__ int sh[256];
    sh[t] = tsum;
    __syncthreads();
    for (int s = 1; s < 256; s <<= 1) {
        int a = (t >= s) ? sh[t - s] : 0;
        __syncthreads();
        sh[t] += a;
        __syncthreads();
    }
    int run = tileSums[tile] + (sh[t] - tsum);
    if (i0 + 0 < N_NODES_C) offsets[i0 + 0] = run; run += c0;
    if (i0 + 1 < N_NODES_C) offsets[i0 + 1] = run; run += c1;
    if (i0 + 2 < N_NODES_C) offsets[i0 + 2] = run; run += c2;
    if (i0 + 3 < N_NODES_C) offsets[i0 + 3] = run;
}

// ============ main pass, PACKED gathers, NO atomics (pos = offs + rank) ============
// recA = {F0',F1',F2', half2(fe0,fe1)}  (9-bit local node id in F mantissa 3/3/3)
// recB = {half2(M0,M1), half2(M2,fe2)}
__global__ __launch_bounds__(256) void main_rank_p(
    const float2* __restrict__ pack,
    const float* __restrict__ prop_E,
    const float* __restrict__ prop_A,
    const float* __restrict__ prop_I22,
    const float* __restrict__ elem_len,
    const float* __restrict__ xhat,
    const float* __restrict__ load,
    const int*   __restrict__ conn,
    const int*   __restrict__ offs,
    const uchar2* __restrict__ rank2,
    float4* __restrict__ recA,
    uint2*  __restrict__ recB,
    Scalars* __restrict__ sc)
{
    int basee = blockIdx.x * (256 * MAIN_EPT) + threadIdx.x;
    double kin = 0.0;

    int2 ij[MAIN_EPT];
    uchar2 rk[MAIN_EPT];
    int oi[MAIN_EPT], oj[MAIN_EPT];
    bool valid[MAIN_EPT];

#pragma unroll
    for (int k = 0; k < MAIN_EPT; ++k) {
        int e = basee + k * 256;
        valid[k] = (e < N_ELEMS_C);
        if (valid[k]) ij[k] = ((const int2*)conn)[e];
    }
#pragma unroll
    for (int k = 0; k < MAIN_EPT; ++k) {
        int e = basee + k * 256;
        if (valid[k]) rk[k] = rank2[e];
    }
    // random 4B reads into a 4MB L2-resident array — issue all 8 early
#pragma unroll
    for (int k = 0; k < MAIN_EPT; ++k) {
        if (valid[k]) {
            oi[k] = offs[ij[k].x];
            oj[k] = offs[ij[k].y];
        }
    }

#pragma unroll
    for (int k = 0; k < MAIN_EPT; ++k) {
        if (!valid[k]) continue;
        int e = basee + k * 256;
        size_t i = (size_t)ij[k].x;
        size_t j = (size_t)ij[k].y;

        const float2* Pi = pack + i * 5;
        const float2* Pj = pack + j * 5;
        float2 i0 = Pi[0], i1 = Pi[1], i2 = Pi[2], i3 = Pi[3], i4 = Pi[4];
        float2 j0 = Pj[0], j1 = Pj[1], j2 = Pj[2], j3 = Pj[3], j4 = Pj[4];

        size_t e3 = 3 * (size_t)e;
        float x0 = xhat[e3 + 0];
        float x1 = xhat[e3 + 1];
        float x2 = xhat[e3 + 2];
        float L  = elem_len[e];
        float E  = prop_E[e];
        float EA = E * prop_A[e];
        float EI = E * prop_I22[e];
        float q0 = load[e3 + 0];
        float q1 = load[e3 + 1];
        float q2 = load[e3 + 2];

        // local axes (matches _local_axes exactly)
        bool  par = fabsf(x1) > 0.99f;
        float r1 = par ? 0.0f : 1.0f;
        float r2 = par ? 1.0f : 0.0f;
        float z0 = x1 * r2 - x2 * r1;
        float z1 = -x0 * r2;
        float z2 =  x0 * r1;
        float zn = fmaxf(sqrtf(z0 * z0 + z1 * z1 + z2 * z2), 1e-8f);
        z0 /= zn; z1 /= zn; z2 /= zn;
        float y0 = z1 * x2 - z2 * x1;
        float y1 = z2 * x0 - z0 * x2;
        float y2 = z0 * x1 - z1 * x0;
        float yn = fmaxf(sqrtf(y0 * y0 + y1 * y1 + y2 * y2), 1e-8f);
        y0 /= yn; y1 /= yn; y2 /= yn;

        float gux_i_ax = i0.x * x0 + i0.y * x1 + i1.x * x2;
        float guz_i_ax = i1.y * x0 + i2.x * x1 + i2.y * x2;
        float kap_i    = i3.x * x0 + i3.y * x1 + i4.x * x2;
        float gux_j_ax = j0.x * x0 + j0.y * x1 + j1.x * x2;
        float guz_j_ax = j1.y * x0 + j2.x * x1 + j2.y * x2;
        float kap_j    = j3.x * x0 + j3.y * x1 + j4.x * x2;

        float eps_i = x0 * gux_i_ax + x2 * guz_i_ax;
        float eps_j = x0 * gux_j_ax + x2 * guz_j_ax;
        float N_avg = 0.5f * EA * (eps_i + eps_j);
        float M_i = EI * kap_i;
        float M_j = EI * kap_j;
        float V = (M_j - M_i) / L;
        float F0 = N_avg * x0 + V * z0;
        float F1 = N_avg * x1 + V * z1;
        float F2 = N_avg * x2 + V * z2;
        float hl = 0.5f * L;
        float fe0 = q0 * hl, fe1 = q1 * hl, fe2 = q2 * hl;

        float wA = __uint_as_float(packH2(fe0, fe1));
        unsigned lii = (unsigned)(ij[k].x & (NPB - 1));
        unsigned lij = (unsigned)(ij[k].y & (NPB - 1));
        int posi = oi[k] + (int)rk[k].x;
        int posj = oj[k] + (int)rk[k].y;

        recA[posi] = make_float4(embedBits( F0, (lii >> 6) & 7u, 3),
                                 embedBits( F1, (lii >> 3) & 7u, 3),
                                 embedBits( F2, lii & 7u, 3), wA);
        recB[posi] = make_uint2(packH2(M_i * y0, M_i * y1), packH2(M_i * y2, fe2));
        recA[posj] = make_float4(embedBits(-F0, (lij >> 6) & 7u, 3),
                                 embedBits(-F1, (lij >> 3) & 7u, 3),
                                 embedBits(-F2, lij & 7u, 3), wA);
        recB[posj] = make_uint2(packH2(M_j * y0, M_j * y1), packH2(M_j * y2, fe2));

        float du_i = z0 * gux_i_ax + z2 * guz_i_ax;
        float du_j = z0 * gux_j_ax + z2 * guz_j_ax;
        float rki = i4.y - du_i;
        float rkj = j4.y - du_j;
        kin += (double)rki * (double)rki + (double)rkj * (double)rkj;
    }

    kin = waveSumD(kin);
    if ((threadIdx.x & 63) == 0) {
        atomicAdd(&sc->S_kin, kin);
    }
}

// ============ main pass, UNPACKED gathers (fallback when pack doesn't fit) ============
__global__ __launch_bounds__(256) void main_rank_u(
    const float* __restrict__ phi,
    const float* __restrict__ grad_ux,
    const float* __restrict__ grad_uz,
    const float* __restrict__ grad_phi,
    const float* __restrict__ prop_E,
    const float* __restrict__ prop_A,
    const float* __restrict__ prop_I22,
    const float* __restrict__ elem_len,
    const float* __restrict__ xhat,
    const float* __restrict__ load,
    const int*   __restrict__ conn,
    const int*   __restrict__ offs,
    const uchar2* __restrict__ rank2,
    float4* __restrict__ recA,
    uint2*  __restrict__ recB,
    Scalars* __restrict__ sc)
{
    int basee = blockIdx.x * (256 * MAIN_EPT) + threadIdx.x;
    double kin = 0.0;

    int2 ij[MAIN_EPT];
    uchar2 rk[MAIN_EPT];
    int oi[MAIN_EPT], oj[MAIN_EPT];
    bool valid[MAIN_EPT];

#pragma unroll
    for (int k = 0; k < MAIN_EPT; ++k) {
        int e = basee + k * 256;
        valid[k] = (e < N_ELEMS_C);
        if (valid[k]) ij[k] = ((const int2*)conn)[e];
    }
#pragma unroll
    for (int k = 0; k < MAIN_EPT; ++k) {
        int e = basee + k * 256;
        if (valid[k]) rk[k] = rank2[e];
    }
#pragma unroll
    for (int k = 0; k < MAIN_EPT; ++k) {
        if (valid[k]) {
            oi[k] = offs[ij[k].x];
            oj[k] = offs[ij[k].y];
        }
    }

#pragma unroll
    for (int k = 0; k < MAIN_EPT; ++k) {
        if (!valid[k]) continue;
        int e = basee + k * 256;
        size_t i = (size_t)ij[k].x;
        size_t j = (size_t)ij[k].y;

        size_t e3 = 3 * (size_t)e;
        float x0 = xhat[e3 + 0];
        float x1 = xhat[e3 + 1];
        float x2 = xhat[e3 + 2];
        float L  = elem_len[e];
        float E  = prop_E[e];
        float EA = E * prop_A[e];
        float EI = E * prop_I22[e];
        float q0 = load[e3 + 0];
        float q1 = load[e3 + 1];
        float q2 = load[e3 + 2];

        bool  par = fabsf(x1) > 0.99f;
        float r1 = par ? 0.0f : 1.0f;
        float r2 = par ? 1.0f : 0.0f;
        float z0 = x1 * r2 - x2 * r1;
        float z1 = -x0 * r2;
        float z2 =  x0 * r1;
        float zn = fmaxf(sqrtf(z0 * z0 + z1 * z1 + z2 * z2), 1e-8f);
        z0 /= zn; z1 /= zn; z2 /= zn;
        float y0 = z1 * x2 - z2 * x1;
        float y1 = z2 * x0 - z0 * x2;
        float y2 = z0 * x1 - z1 * x0;
        float yn = fmaxf(sqrtf(y0 * y0 + y1 * y1 + y2 * y2), 1e-8f);
        y0 /= yn; y1 /= yn; y2 /= yn;

        size_t i3 = 3 * i, j3 = 3 * j;
        float gux_i_ax = grad_ux[i3 + 0] * x0 + grad_ux[i3 + 1] * x1 + grad_ux[i3 + 2] * x2;
        float gux_j_ax = grad_ux[j3 + 0] * x0 + grad_ux[j3 + 1] * x1 + grad_ux[j3 + 2] * x2;
        float guz_i_ax = grad_uz[i3 + 0] * x0 + grad_uz[i3 + 1] * x1 + grad_uz[i3 + 2] * x2;
        float guz_j_ax = grad_uz[j3 + 0] * x0 + grad_uz[j3 + 1] * x1 + grad_uz[j3 + 2] * x2;
        float kap_i    = grad_phi[i3 + 0] * x0 + grad_phi[i3 + 1] * x1 + grad_phi[i3 + 2] * x2;
        float kap_j    = grad_phi[j3 + 0] * x0 + grad_phi[j3 + 1] * x1 + grad_phi[j3 + 2] * x2;

        float eps_i = x0 * gux_i_ax + x2 * guz_i_ax;
        float eps_j = x0 * gux_j_ax + x2 * guz_j_ax;
        float N_avg = 0.5f * EA * (eps_i + eps_j);
        float M_i = EI * kap_i;
        float M_j = EI * kap_j;
        float V = (M_j - M_i) / L;
        float F0 = N_avg * x0 + V * z0;
        float F1 = N_avg * x1 + V * z1;
        float F2 = N_avg * x2 + V * z2;
        float hl = 0.5f * L;
        float fe0 = q0 * hl, fe1 = q1 * hl, fe2 = q2 * hl;

        float wA = __uint_as_float(packH2(fe0, fe1));
        unsigned lii = (unsigned)(ij[k].x & (NPB - 1));
        unsigned lij = (unsigned)(ij[k].y & (NPB - 1));
        int posi = oi[k] + (int)rk[k].x;
        int posj = oj[k] + (int)rk[k].y;

        recA[posi] = make_float4(embedBits( F0, (lii >> 6) & 7u, 3),
                                 embedBits( F1, (lii >> 3) & 7u, 3),
                                 embedBits( F2, lii & 7u, 3), wA);
        recB[posi] = make_uint2(packH2(M_i * y0, M_i * y1), packH2(M_i * y2, fe2));
        recA[posj] = make_float4(embedBits(-F0, (lij >> 6) & 7u, 3),
                                 embedBits(-F1, (lij >> 3) & 7u, 3),
                                 embedBits(-F2, lij & 7u, 3), wA);
        recB[posj] = make_uint2(packH2(M_j * y0, M_j * y1), packH2(M_j * y2, fe2));

        float du_i = z0 * gux_i_ax + z2 * guz_i_ax;
        float du_j = z0 * gux_j_ax + z2 * guz_j_ax;
        float rki = phi[i] - du_i;
        float rkj = phi[j] - du_j;
        kin += (double)rki * (double)rki + (double)rkj * (double)rkj;
    }

    kin = waveSumD(kin);
    if ((threadIdx.x & 63) == 0) {
        atomicAdd(&sc->S_kin, kin);
    }
}

// ============ node pass: coalesced streaming + ROTATED-FIELD LDS atomics ============
// No scan, no binary search. Lane rotates its field order by (lane % 9) so the
// ~8 consecutive lanes sharing a node hit 9 DIFFERENT addresses each round:
// no same-address serialization, 9 independent fire-and-forget ds_add_f32.
__global__ __launch_bounds__(256) void node_rot(
    const float* __restrict__ bc_disp,
    const float* __restrict__ bc_rot,
    const int*   __restrict__ offs,   // start offsets
    const float4* __restrict__ recA,
    const uint2*  __restrict__ recB,
    Scalars* __restrict__ sc)
{
    __shared__ float bins[NPB * 9];     // 18 KB
    const int n0  = blockIdx.x * NPB;
    const int cnt = min(NPB, N_NODES_C - n0);

    for (int t = threadIdx.x; t < NPB * 9; t += 256) bins[t] = 0.0f;
    __syncthreads();

    const int beg = offs[n0];
    const int end = (n0 + cnt < N_NODES_C) ? offs[n0 + cnt] : N_ENDP_C;
    const int rot = (int)(threadIdx.x % 9u);

    for (int r = beg + threadIdx.x; r < end; r += 256) {
        float4 a = recA[r];
        uint2  b = recB[r];
        unsigned u0 = __float_as_uint(a.x);
        unsigned u1 = __float_as_uint(a.y);
        unsigned u2 = __float_as_uint(a.z);
        int li = (int)(((u0 & 7u) << 6) | ((u1 & 7u) << 3) | (u2 & 7u));
        unsigned ua = __float_as_uint(a.w);

        float v[9];
        v[0] = a.x; v[1] = a.y; v[2] = a.z;
        v[3] = lowH(b.x); v[4] = highH(b.x); v[5] = lowH(b.y);
        v[6] = lowH(ua);  v[7] = highH(ua);  v[8] = highH(b.y);

        float* bp = &bins[li * 9];
#pragma unroll
        for (int f = 0; f < 9; ++f) {
            int ff = f + rot; if (ff >= 9) ff -= 9;
            atomicAdd(bp + ff, v[ff]);
        }
    }
    __syncthreads();

    double sFext = 0.0, sForce = 0.0, sMom = 0.0, sNeu = 0.0;
    int cfd = 0, cfr = 0, cpin = 0;

    for (int t = threadIdx.x; t < cnt; t += 256) {
        int n = n0 + t;
        float bd = bc_disp[n];
        float br = bc_rot[n];
        bool fd  = bd < 0.5f;
        bool fr  = br < 0.5f;
        bool pin = (bd > 0.5f) && (br < 0.5f);

        const float* bp = &bins[t * 9];
        float fi0 = bp[0], fi1 = bp[1], fi2 = bp[2];
        float m0  = bp[3], m1  = bp[4], m2  = bp[5];
        float fe0 = bp[6], fe1 = bp[7], fe2 = bp[8];

        double fesq = (double)fe0 * fe0 + (double)fe1 * fe1 + (double)fe2 * fe2;
        double s0 = (double)(fi0 + fe0);
        double s1 = (double)(fi1 + fe1);
        double s2 = (double)(fi2 + fe2);
        double fsq = s0 * s0 + s1 * s1 + s2 * s2;
        double msq = (double)m0 * m0 + (double)m1 * m1 + (double)m2 * m2;

        if (fd)  { sFext += fesq; sForce += fsq; cfd++; }
        if (fr)  { sMom += msq; cfr++; }
        if (pin) { sNeu += msq; cpin++; }
    }

    sFext  = waveSumD(sFext);
    sForce = waveSumD(sForce);
    sMom   = waveSumD(sMom);
    sNeu   = waveSumD(sNeu);
    cfd  = waveSumI(cfd);
    cfr  = waveSumI(cfr);
    cpin = waveSumI(cpin);

    if ((threadIdx.x & 63) == 0) {
        atomicAdd(&sc->S_Fext,  sFext);
        atomicAdd(&sc->S_force, sForce);
        atomicAdd(&sc->S_mom,   sMom);
        atomicAdd(&sc->S_neu,   sNeu);
        atomicAdd(&sc->n_fd,  (unsigned long long)cfd);
        atomicAdd(&sc->n_fr,  (unsigned long long)cfr);
        atomicAdd(&sc->n_pin, (unsigned long long)cpin);
    }
}

// ============ Tier B kernels (verified fallback) ============

__global__ __launch_bounds__(256) void hist_scalars(
    const int* __restrict__ conn,
    const float* __restrict__ elem_len,
    const float* __restrict__ load,
    int* __restrict__ counts,
    Scalars* __restrict__ sc)
{
    int e = blockIdx.x * blockDim.x + threadIdx.x;
    double lsum = 0.0;
    float qm = 0.0f, lm = 0.0f;
    if (e < N_ELEMS_C) {
        int2 ij = ((const int2*)conn)[e];
        atomicAdd(&counts[ij.x], 1);
        atomicAdd(&counts[ij.y], 1);
        float L = elem_len[e];
        float q0 = load[3 * (size_t)e + 0];
        float q1 = load[3 * (size_t)e + 1];
        float q2 = load[3 * (size_t)e + 2];
        lsum = (double)L;
        lm = L;
        qm = fmaxf(fmaxf(fabsf(q0), fabsf(q1)), fabsf(q2));
    }
    lsum = waveSumD(lsum);
    qm = waveMaxF(qm);
    lm = waveMaxF(lm);
    if ((threadIdx.x & 63) == 0) {
        atomicAdd(&sc->L_sum, lsum);
        atomicMax(&sc->q_max_bits, __float_as_int(qm));
        atomicMax(&sc->L_max_bits, __float_as_int(lm));
    }
}

__global__ __launch_bounds__(256) void fill_csr(
    const int* __restrict__ conn,
    const int* __restrict__ offsets,
    int* __restrict__ counts,
    int* __restrict__ eidside)
{
    int e = blockIdx.x * blockDim.x + threadIdx.x;
    if (e >= N_ELEMS_C) return;
    int2 ij = ((const int2*)conn)[e];
    int oi = atomicSub(&counts[ij.x], 1) - 1;
    eidside[offsets[ij.x] + oi] = (e << 1);
    int oj = atomicSub(&counts[ij.y], 1) - 1;
    eidside[offsets[ij.y] + oj] = (e << 1) | 1;
}

__global__ __launch_bounds__(256) void node_reduce_csr(
    const float* __restrict__ phi,
    const float* __restrict__ grad_ux,
    const float* __restrict__ grad_uz,
    const float* __restrict__ grad_phi,
    const float* __restrict__ prop_E,
    const float* __restrict__ prop_A,
    const float* __restrict__ prop_I22,
    const float* __restrict__ elem_len,
    const float* __restrict__ xhat,
    const float* __restrict__ load,
    const int*   __restrict__ conn,
    const float* __restrict__ bc_disp,
    const float* __restrict__ bc_rot,
    const int*   __restrict__ offsets,
    const int*   __restrict__ eidside,
    Scalars* __restrict__ sc)
{
    int n = blockIdx.x * blockDim.x + threadIdx.x;
    double sFext = 0.0, sForce = 0.0, sMom = 0.0, sNeu = 0.0, kin = 0.0;
    bool fd = false, fr = false, pin = false;

    if (n < N_NODES_C) {
        float bd = bc_disp[n];
        float br = bc_rot[n];
        fd  = bd < 0.5f;
        fr  = br < 0.5f;
        pin = (bd > 0.5f) && (br < 0.5f);

        float phin = phi[n];
        size_t b3 = 3 * (size_t)n;
        float ux0 = grad_ux[b3 + 0], ux1 = grad_ux[b3 + 1], ux2 = grad_ux[b3 + 2];
        float uz0 = grad_uz[b3 + 0], uz1 = grad_uz[b3 + 1], uz2 = grad_uz[b3 + 2];
        float gp0 = grad_phi[b3 + 0], gp1 = grad_phi[b3 + 1], gp2 = grad_phi[b3 + 2];

        int beg = offsets[n];
        int end = (n == N_NODES_C - 1) ? N_ENDP_C : offsets[n + 1];

        float fi0 = 0.f, fi1 = 0.f, fi2 = 0.f;
        float m0 = 0.f, m1 = 0.f, m2 = 0.f;
        float fe0 = 0.f, fe1 = 0.f, fe2 = 0.f;

        for (int k = beg; k < end; ++k) {
            int es = eidside[k];
            int e  = es >> 1;
            int s  = es & 1;
            int2 c = ((const int2*)conn)[e];
            size_t other = (size_t)(s ? c.x : c.y);

            size_t e3 = 3 * (size_t)e;
            float x0 = xhat[e3 + 0];
            float x1 = xhat[e3 + 1];
            float x2 = xhat[e3 + 2];
            float L  = elem_len[e];
            float E  = prop_E[e];
            float EA = E * prop_A[e];
            float EI = E * prop_I22[e];
            float q0 = load[e3 + 0];
            float q1 = load[e3 + 1];
            float q2 = load[e3 + 2];

            bool  par = fabsf(x1) > 0.99f;
            float r1 = par ? 0.0f : 1.0f;
            float r2 = par ? 1.0f : 0.0f;
            float z0 = x1 * r2 - x2 * r1;
            float z1 = -x0 * r2;
            float z2 =  x0 * r1;
            float zn = fmaxf(sqrtf(z0 * z0 + z1 * z1 + z2 * z2), 1e-8f);
            z0 /= zn; z1 /= zn; z2 /= zn;
            float y0 = z1 * x2 - z2 * x1;
            float y1 = z2 * x0 - z0 * x2;
            float y2 = z0 * x1 - z1 * x0;
            float yn = fmaxf(sqrtf(y0 * y0 + y1 * y1 + y2 * y2), 1e-8f);
            y0 /= yn; y1 /= yn; y2 /= yn;

            float own_ux_ax = ux0 * x0 + ux1 * x1 + ux2 * x2;
            float own_uz_ax = uz0 * x0 + uz1 * x1 + uz2 * x2;
            float kap_own   = gp0 * x0 + gp1 * x1 + gp2 * x2;

            size_t o3 = 3 * other;
            float oth_ux_ax = grad_ux[o3 + 0] * x0 + grad_ux[o3 + 1] * x1 + grad_ux[o3 + 2] * x2;
            float oth_uz_ax = grad_uz[o3 + 0] * x0 + grad_uz[o3 + 1] * x1 + grad_uz[o3 + 2] * x2;
            float kap_oth   = grad_phi[o3 + 0] * x0 + grad_phi[o3 + 1] * x1 + grad_phi[o3 + 2] * x2;

            float eps_own = x0 * own_ux_ax + x2 * own_uz_ax;
            float eps_oth = x0 * oth_ux_ax + x2 * oth_uz_ax;
            float N_avg = 0.5f * EA * (eps_own + eps_oth);
            float M_own = EI * kap_own;
            float M_oth = EI * kap_oth;
            float Vz = (M_oth - M_own) / L;
            float t = s ? -1.0f : 1.0f;

            fi0 += t * N_avg * x0 + Vz * z0;
            fi1 += t * N_avg * x1 + Vz * z1;
            fi2 += t * N_avg * x2 + Vz * z2;
            m0  += M_own * y0;
            m1  += M_own * y1;
            m2  += M_own * y2;
            float hl = 0.5f * L;
            fe0 += q0 * hl;
            fe1 += q1 * hl;
            fe2 += q2 * hl;

            float du = z0 * own_ux_ax + z2 * own_uz_ax;
            float rk = phin - du;
            kin += (double)rk * (double)rk;
        }

        double fesq = (double)fe0 * fe0 + (double)fe1 * fe1 + (double)fe2 * fe2;
        double s0 = (double)(fi0 + fe0);
        double s1 = (double)(fi1 + fe1);
        double s2 = (double)(fi2 + fe2);
        double fsq = s0 * s0 + s1 * s1 + s2 * s2;
        double msq = (double)m0 * m0 + (double)m1 * m1 + (double)m2 * m2;

        if (fd)  { sFext = fesq; sForce = fsq; }
        if (fr)  { sMom = msq; }
        if (pin) { sNeu = msq; }
    }

    unsigned long long cfd  = __popcll(__ballot(fd));
    unsigned long long cfr  = __popcll(__ballot(fr));
    unsigned long long cpin = __popcll(__ballot(pin));

    sFext  = waveSumD(sFext);
    sForce = waveSumD(sForce);
    sMom   = waveSumD(sMom);
    sNeu   = waveSumD(sNeu);
    kin    = waveSumD(kin);

    if ((threadIdx.x & 63) == 0) {
        atomicAdd(&sc->S_Fext,  sFext);
        atomicAdd(&sc->S_force, sForce);
        atomicAdd(&sc->S_mom,   sMom);
        atomicAdd(&sc->S_neu,   sNeu);
        atomicAdd(&sc->S_kin,   kin);
        atomicAdd(&sc->n_fd,  cfd);
        atomicAdd(&sc->n_fr,  cfr);
        atomicAdd(&sc->n_pin, cpin);
    }
}

// ============ finalize ============

__global__ void finalize_kernel(const Scalars* __restrict__ sc, float* __restrict__ out)
{
    double n_fd = (double)(sc->n_fd > 0ull ? sc->n_fd : 1ull);
    double n_fr = (double)(sc->n_fr > 0ull ? sc->n_fr : 1ull);

    double F_char = sqrt(sc->S_Fext / (3.0 * n_fd));
    if (F_char < 1.0) F_char = 1.0;

    double q_max = (double)__int_as_float(sc->q_max_bits);
    if (q_max < 1.0) q_max = 1.0;
    double L_max = (double)__int_as_float(sc->L_max_bits);
    double M_char = q_max * L_max * sc->L_sum / 8.0;
    if (M_char < 1.0) M_char = 1.0;

    double L_force  = sc->S_force / (3.0 * n_fd) / (F_char * F_char);
    double L_moment = sc->S_mom   / (3.0 * n_fr) / (M_char * M_char);
    double L_neu = 0.0;
    if (sc->n_pin > 0ull) {
        L_neu = sc->S_neu / (3.0 * (double)sc->n_pin) / (M_char * M_char);
    }
    double L_kin = 0.5 * sc->S_kin / (double)N_ELEMS_C;

    out[0] = (float)(1.0 * L_force + 1.0 * L_moment + 1.0 * L_neu + 0.1 * L_kin);
}

// ============ host ============

extern "C" void kernel_launch(void* const* d_in, const int* in_sizes, int n_in,
                              void* d_out, int out_size, void* d_ws, size_t ws_size,
                              hipStream_t stream) {
    const float* phi       = (const float*)d_in[0];
    const float* grad_ux   = (const float*)d_in[1];
    const float* grad_uz   = (const float*)d_in[2];
    const float* grad_phi  = (const float*)d_in[3];
    const float* prop_E    = (const float*)d_in[4];
    const float* prop_A    = (const float*)d_in[5];
    const float* prop_I22  = (const float*)d_in[6];
    const float* elem_len  = (const float*)d_in[7];
    const float* elem_dir  = (const float*)d_in[8];
    const float* elem_load = (const float*)d_in[9];
    const float* bc_disp   = (const float*)d_in[10];
    const float* bc_rot    = (const float*)d_in[11];
    const int*   conn      = (const int*)d_in[12];

    const size_t HDR     = 65536;                      // sc + tileSums
    const size_t szNode  = (size_t)N_NODES_C * 4;      //   4 MB (offsets / counts)
    const size_t szRank  = (size_t)N_ELEMS_C * 2;      //   8 MB (uchar2/elem)
    const size_t szPack  = (size_t)N_NODES_C * 40;     //  40 MB (10 floats tight)
    const size_t szRecA  = (size_t)N_ENDP_C * 16;      // 128 MB
    const size_t szRecB  = (size_t)N_ENDP_C * 8;       //  64 MB

    const size_t needRp = HDR + szNode + szRank + szPack + szRecA + szRecB; // ~244.1 MB
    const size_t needRu = HDR + szNode + szRank + szRecA + szRecB;          // ~204.1 MB

    const int egrid = (N_ELEMS_C + 255) / 256;
    const int ngrid = (N_NODES_C + 255) / 256;
    const int hgrid = (N_ELEMS_C + 256 * HIST_EPT - 1) / (256 * HIST_EPT);
    const int mgrid = (N_ELEMS_C + 256 * MAIN_EPT - 1) / (256 * MAIN_EPT);

    if (ws_size >= needRu) {
        const bool packed = (ws_size >= needRp);

        char* p = (char*)d_ws;
        Scalars* sc   = (Scalars*)p;
        int* tileSums = (int*)(p + 128);
        p += HDR;
        int* offsets  = (int*)p;      p += szNode;
        uchar2* rank2 = (uchar2*)p;   p += szRank;
        float2* pack  = (float2*)p;   if (packed) p += szPack;
        float4* recA  = (float4*)p;   p += szRecA;
        uint2*  recB  = (uint2*)p;
        int* counts   = (int*)recA;   // aliased: dead after scan_within, before recA writes

        hipMemsetAsync(sc, 0, 128, stream);
        hipMemsetAsync(counts, 0, szNode, stream);

        if (packed) {
            pack_nodes10<<<ngrid, 256, 0, stream>>>(phi, grad_ux, grad_uz, grad_phi, pack);
        }
        hist_rank<<<hgrid, 256, 0, stream>>>(conn, elem_len, elem_load, counts, rank2, sc);
        tile_sum<<<N_TILES, 256, 0, stream>>>(counts, tileSums);
        scan_tiles<<<1, 1024, 0, stream>>>(tileSums);
        scan_within<<<N_TILES, 256, 0, stream>>>(counts, tileSums, offsets);
        if (packed) {
            main_rank_p<<<mgrid, 256, 0, stream>>>(
                pack, prop_E, prop_A, prop_I22, elem_len, elem_dir, elem_load, conn,
                offsets, rank2, recA, recB, sc);
        } else {
            main_rank_u<<<mgrid, 256, 0, stream>>>(
                phi, grad_ux, grad_uz, grad_phi,
                prop_E, prop_A, prop_I22, elem_len, elem_dir, elem_load, conn,
                offsets, rank2, recA, recB, sc);
        }
        node_rot<<<N_NBLOCKS, 256, 0, stream>>>(bc_disp, bc_rot, offsets, recA, recB, sc);
        finalize_kernel<<<1, 1, 0, stream>>>(sc, (float*)d_out);
    } else {
        // ---- Tier B (verified fallback) ----
        char* p = (char*)d_ws;
        int* counts   = (int*)p;      p += szNode;
        Scalars* sc   = (Scalars*)p;  p += 128;
        int* offsets  = (int*)p;      p += szNode;
        int* tileSums = (int*)p;      p += 4096;
        int* eidside  = (int*)p;

        hipMemsetAsync(counts, 0, szNode + 128, stream);
        hist_scalars<<<egrid, 256, 0, stream>>>(conn, elem_len, elem_load, counts, sc);
        tile_sum<<<N_TILES, 256, 0, stream>>>(counts, tileSums);
        scan_tiles<<<1, 1024, 0, stream>>>(tileSums);
        scan_within<<<N_TILES, 256, 0, stream>>>(counts, tileSums, offsets);
        fill_csr<<<egrid, 256, 0, stream>>>(conn, offsets, counts, eidside);
        node_reduce_csr<<<ngrid, 256, 0, stream>>>(
            phi, grad_ux, grad_uz, grad_phi,
            prop_E, prop_A, prop_I22, elem_len, elem_dir, elem_load, conn,
            bc_disp, bc_rot, offsets, eidside, sc);
        finalize_kernel<<<1, 1, 0, stream>>>(sc, (float*)d_out);
    }
}

// Round 7
// 1871.461 us; speedup vs baseline: 1.0040x; 1.0040x over previous
//
#include <hip/hip_runtime.h>
#include <hip/hip_fp16.h>

#define N_NODES_C 1000000
#define N_ELEMS_C 4000000
#define N_ENDP_C  (2 * N_ELEMS_C)
#define TILE 1024
#define N_TILES ((N_NODES_C + TILE - 1) / TILE)   // 977
#define HIST_EPT 8
#define MAIN_EPT 4
#define NPB 512                                    // nodes per block in node_mlp
#define N_NBLOCKS ((N_NODES_C + NPB - 1) / NPB)    // 1954
#define RB 4                                       // records per thread per iter

struct Scalars {
    double S_kin;
    double L_sum;
    double S_Fext;
    double S_force;
    double S_mom;
    double S_neu;
    unsigned long long n_fd;
    unsigned long long n_fr;
    unsigned long long n_pin;
    int q_max_bits;
    int L_max_bits;
};

__device__ __forceinline__ double waveSumD(double v) {
    for (int off = 32; off > 0; off >>= 1) v += __shfl_down(v, off, 64);
    return v;
}
__device__ __forceinline__ float waveMaxF(float v) {
    for (int off = 32; off > 0; off >>= 1) v = fmaxf(v, __shfl_down(v, off, 64));
    return v;
}
__device__ __forceinline__ int waveSumI(int v) {
    for (int off = 32; off > 0; off >>= 1) v += __shfl_down(v, off, 64);
    return v;
}
__device__ __forceinline__ unsigned packH2(float a, float b) {
    return (unsigned)__half_as_ushort(__float2half(a)) |
           ((unsigned)__half_as_ushort(__float2half(b)) << 16);
}
__device__ __forceinline__ float lowH(unsigned u)  { return __half2float(__ushort_as_half((unsigned short)(u & 0xFFFFu))); }
__device__ __forceinline__ float highH(unsigned u) { return __half2float(__ushort_as_half((unsigned short)(u >> 16))); }
// embed nb low bits into float mantissa (rel err <= 2^-(23-nb), harmless)
__device__ __forceinline__ float embedBits(float f, unsigned bits, unsigned nb) {
    unsigned u = __float_as_uint(f);
    u = (u & ~((1u << nb) - 1u)) | bits;
    return __uint_as_float(u);
}

// ============ node-data pack: 10 floats tight (40B) per node ============
// layout: ux0 ux1 | ux2 uz0 | uz1 uz2 | gp0 gp1 | gp2 phi
__global__ __launch_bounds__(256) void pack_nodes10(
    const float* __restrict__ phi,
    const float* __restrict__ grad_ux,
    const float* __restrict__ grad_uz,
    const float* __restrict__ grad_phi,
    float2* __restrict__ pack)          // 5 float2 per node
{
    int n = blockIdx.x * blockDim.x + threadIdx.x;
    if (n >= N_NODES_C) return;
    size_t n3 = 3 * (size_t)n;
    float ux0 = grad_ux[n3 + 0], ux1 = grad_ux[n3 + 1], ux2 = grad_ux[n3 + 2];
    float uz0 = grad_uz[n3 + 0], uz1 = grad_uz[n3 + 1], uz2 = grad_uz[n3 + 2];
    float gp0 = grad_phi[n3 + 0], gp1 = grad_phi[n3 + 1], gp2 = grad_phi[n3 + 2];
    float ph  = phi[n];
    float2* P = pack + (size_t)n * 5;
    P[0] = make_float2(ux0, ux1);
    P[1] = make_float2(ux2, uz0);
    P[2] = make_float2(uz1, uz2);
    P[3] = make_float2(gp0, gp1);
    P[4] = make_float2(gp2, ph);
}

// ============ hist + RANK: single atomic pass (returning atomicAdd) ============
__global__ __launch_bounds__(256) void hist_rank(
    const int* __restrict__ conn,
    const float* __restrict__ elem_len,
    const float* __restrict__ load,
    int* __restrict__ counts,
    uchar2* __restrict__ rank2,
    Scalars* __restrict__ sc)
{
    int base = blockIdx.x * (256 * HIST_EPT) + threadIdx.x;
    double lsum = 0.0;
    float qm = 0.0f, lm = 0.0f;

    int2 ij[HIST_EPT];
    int ri[HIST_EPT], rj[HIST_EPT];
    bool valid[HIST_EPT];
#pragma unroll
    for (int k = 0; k < HIST_EPT; ++k) {
        int e = base + k * 256;
        valid[k] = (e < N_ELEMS_C);
        if (valid[k]) ij[k] = ((const int2*)conn)[e];
    }
    // 16 independent returning atomics in flight
#pragma unroll
    for (int k = 0; k < HIST_EPT; ++k) {
        if (valid[k]) {
            ri[k] = atomicAdd(&counts[ij[k].x], 1);
            rj[k] = atomicAdd(&counts[ij[k].y], 1);
        }
    }
#pragma unroll
    for (int k = 0; k < HIST_EPT; ++k) {
        int e = base + k * 256;
        if (valid[k]) {
            rank2[e] = make_uchar2((unsigned char)min(ri[k], 255),
                                   (unsigned char)min(rj[k], 255));
        }
    }
#pragma unroll
    for (int k = 0; k < HIST_EPT; ++k) {
        int e = base + k * 256;
        if (valid[k]) {
            float L = elem_len[e];
            float q0 = load[3 * (size_t)e + 0];
            float q1 = load[3 * (size_t)e + 1];
            float q2 = load[3 * (size_t)e + 2];
            lsum += (double)L;
            lm = fmaxf(lm, L);
            qm = fmaxf(qm, fmaxf(fmaxf(fabsf(q0), fabsf(q1)), fabsf(q2)));
        }
    }

    lsum = waveSumD(lsum);
    qm = waveMaxF(qm);
    lm = waveMaxF(lm);
    if ((threadIdx.x & 63) == 0) {
        atomicAdd(&sc->L_sum, lsum);
        atomicMax(&sc->q_max_bits, __float_as_int(qm));
        atomicMax(&sc->L_max_bits, __float_as_int(lm));
    }
}

// ============ scan kernels (verified) ============

__global__ __launch_bounds__(256) void tile_sum(
    const int* __restrict__ counts, int* __restrict__ tileSums)
{
    int tile = blockIdx.x;
    int base = tile * TILE;
    int s = 0;
    for (int k = threadIdx.x; k < TILE; k += 256) {
        int idx = base + k;
        s += (idx < N_NODES_C) ? counts[idx] : 0;
    }
    s = waveSumI(s);
    __shared__ int sh[4];
    if ((threadIdx.x & 63) == 0) sh[threadIdx.x >> 6] = s;
    __syncthreads();
    if (threadIdx.x == 0) tileSums[tile] = sh[0] + sh[1] + sh[2] + sh[3];
}

__global__ __launch_bounds__(1024) void scan_tiles(int* __restrict__ tileSums)
{
    __shared__ int sh[1024];
    int t = threadIdx.x;
    int v = (t < N_TILES) ? tileSums[t] : 0;
    sh[t] = v;
    __syncthreads();
    for (int s = 1; s < 1024; s <<= 1) {
        int a = (t >= s) ? sh[t - s] : 0;
        __syncthreads();
        sh[t] += a;
        __syncthreads();
    }
    if (t < N_TILES) tileSums[t] = sh[t] - v;   // exclusive over tiles
}

// EXCLUSIVE scan -> offsets (start offsets)
__global__ __launch_bounds__(256) void scan_within(
    const int* __restrict__ counts, const int* __restrict__ tileSums,
    int* __restrict__ offsets)
{
    int tile = blockIdx.x;
    int base = tile * TILE;
    int t = threadIdx.x;
    int i0 = base + t * 4;
    int c0 = (i0 + 0 < N_NODES_C) ? counts[i0 + 0] : 0;
    int c1 = (i0 + 1 < N_NODES_C) ? counts[i0 + 1] : 0;
    int c2 = (i0 + 2 < N_NODES_C) ? counts[i0 + 2] : 0;
    int c3 = (i0 + 3 < N_NODES_C) ? counts[i0 + 3] : 0;
    int tsum = c0 + c1 + c2 + c3;
    __shared__ int sh[256];
    sh[t] = tsum;
    __syncthreads();
    for (int s = 1; s < 256; s <<= 1) {
        int a = (t >= s) ? sh[t - s] : 0;
        __syncthreads();
        sh[t] += a;
        __syncthreads();
    }
    int run = tileSums[tile] + (sh[t] - tsum);
    if (i0 + 0 < N_NODES_C) offsets[i0 + 0] = run; run += c0;
    if (i0 + 1 < N_NODES_C) offsets[i0 + 1] = run; run += c1;
    if (i0 + 2 < N_NODES_C) offsets[i0 + 2] = run; run += c2;
    if (i0 + 3 < N_NODES_C) offsets[i0 + 3] = run;
}

// ============ main pass, PACKED gathers, NO atomics (pos = offs + rank) ============
// recA = {F0',F1',F2', half2(fe0,fe1)}  (9-bit local node id in F mantissa 3/3/3)
// recB = {half2(M0,M1), half2(M2,fe2)}
__global__ __launch_bounds__(256) void main_rank_p(
    const float2* __restrict__ pack,
    const float* __restrict__ prop_E,
    const float* __restrict__ prop_A,
    const float* __restrict__ prop_I22,
    const float* __restrict__ elem_len,
    const float* __restrict__ xhat,
    const float* __restrict__ load,
    const int*   __restrict__ conn,
    const int*   __restrict__ offs,
    const uchar2* __restrict__ rank2,
    float4* __restrict__ recA,
    uint2*  __restrict__ recB,
    Scalars* __restrict__ sc)
{
    int basee = blockIdx.x * (256 * MAIN_EPT) + threadIdx.x;
    double kin = 0.0;

    int2 ij[MAIN_EPT];
    uchar2 rk[MAIN_EPT];
    int oi[MAIN_EPT], oj[MAIN_EPT];
    bool valid[MAIN_EPT];

#pragma unroll
    for (int k = 0; k < MAIN_EPT; ++k) {
        int e = basee + k * 256;
        valid[k] = (e < N_ELEMS_C);
        if (valid[k]) ij[k] = ((const int2*)conn)[e];
    }
#pragma unroll
    for (int k = 0; k < MAIN_EPT; ++k) {
        int e = basee + k * 256;
        if (valid[k]) rk[k] = rank2[e];
    }
    // random 4B reads into a 4MB L2-resident array — issue all 8 early
#pragma unroll
    for (int k = 0; k < MAIN_EPT; ++k) {
        if (valid[k]) {
            oi[k] = offs[ij[k].x];
            oj[k] = offs[ij[k].y];
        }
    }

#pragma unroll
    for (int k = 0; k < MAIN_EPT; ++k) {
        if (!valid[k]) continue;
        int e = basee + k * 256;
        size_t i = (size_t)ij[k].x;
        size_t j = (size_t)ij[k].y;

        const float2* Pi = pack + i * 5;
        const float2* Pj = pack + j * 5;
        float2 i0 = Pi[0], i1 = Pi[1], i2 = Pi[2], i3 = Pi[3], i4 = Pi[4];
        float2 j0 = Pj[0], j1 = Pj[1], j2 = Pj[2], j3 = Pj[3], j4 = Pj[4];

        size_t e3 = 3 * (size_t)e;
        float x0 = xhat[e3 + 0];
        float x1 = xhat[e3 + 1];
        float x2 = xhat[e3 + 2];
        float L  = elem_len[e];
        float E  = prop_E[e];
        float EA = E * prop_A[e];
        float EI = E * prop_I22[e];
        float q0 = load[e3 + 0];
        float q1 = load[e3 + 1];
        float q2 = load[e3 + 2];

        // local axes (matches _local_axes exactly)
        bool  par = fabsf(x1) > 0.99f;
        float r1 = par ? 0.0f : 1.0f;
        float r2 = par ? 1.0f : 0.0f;
        float z0 = x1 * r2 - x2 * r1;
        float z1 = -x0 * r2;
        float z2 =  x0 * r1;
        float zn = fmaxf(sqrtf(z0 * z0 + z1 * z1 + z2 * z2), 1e-8f);
        z0 /= zn; z1 /= zn; z2 /= zn;
        float y0 = z1 * x2 - z2 * x1;
        float y1 = z2 * x0 - z0 * x2;
        float y2 = z0 * x1 - z1 * x0;
        float yn = fmaxf(sqrtf(y0 * y0 + y1 * y1 + y2 * y2), 1e-8f);
        y0 /= yn; y1 /= yn; y2 /= yn;

        float gux_i_ax = i0.x * x0 + i0.y * x1 + i1.x * x2;
        float guz_i_ax = i1.y * x0 + i2.x * x1 + i2.y * x2;
        float kap_i    = i3.x * x0 + i3.y * x1 + i4.x * x2;
        float gux_j_ax = j0.x * x0 + j0.y * x1 + j1.x * x2;
        float guz_j_ax = j1.y * x0 + j2.x * x1 + j2.y * x2;
        float kap_j    = j3.x * x0 + j3.y * x1 + j4.x * x2;

        float eps_i = x0 * gux_i_ax + x2 * guz_i_ax;
        float eps_j = x0 * gux_j_ax + x2 * guz_j_ax;
        float N_avg = 0.5f * EA * (eps_i + eps_j);
        float M_i = EI * kap_i;
        float M_j = EI * kap_j;
        float V = (M_j - M_i) / L;
        float F0 = N_avg * x0 + V * z0;
        float F1 = N_avg * x1 + V * z1;
        float F2 = N_avg * x2 + V * z2;
        float hl = 0.5f * L;
        float fe0 = q0 * hl, fe1 = q1 * hl, fe2 = q2 * hl;

        float wA = __uint_as_float(packH2(fe0, fe1));
        unsigned lii = (unsigned)(ij[k].x & (NPB - 1));
        unsigned lij = (unsigned)(ij[k].y & (NPB - 1));
        int posi = oi[k] + (int)rk[k].x;
        int posj = oj[k] + (int)rk[k].y;

        recA[posi] = make_float4(embedBits( F0, (lii >> 6) & 7u, 3),
                                 embedBits( F1, (lii >> 3) & 7u, 3),
                                 embedBits( F2, lii & 7u, 3), wA);
        recB[posi] = make_uint2(packH2(M_i * y0, M_i * y1), packH2(M_i * y2, fe2));
        recA[posj] = make_float4(embedBits(-F0, (lij >> 6) & 7u, 3),
                                 embedBits(-F1, (lij >> 3) & 7u, 3),
                                 embedBits(-F2, lij & 7u, 3), wA);
        recB[posj] = make_uint2(packH2(M_j * y0, M_j * y1), packH2(M_j * y2, fe2));

        float du_i = z0 * gux_i_ax + z2 * guz_i_ax;
        float du_j = z0 * gux_j_ax + z2 * guz_j_ax;
        float rki = i4.y - du_i;
        float rkj = j4.y - du_j;
        kin += (double)rki * (double)rki + (double)rkj * (double)rkj;
    }

    kin = waveSumD(kin);
    if ((threadIdx.x & 63) == 0) {
        atomicAdd(&sc->S_kin, kin);
    }
}

// ============ main pass, UNPACKED gathers (fallback when pack doesn't fit) ============
__global__ __launch_bounds__(256) void main_rank_u(
    const float* __restrict__ phi,
    const float* __restrict__ grad_ux,
    const float* __restrict__ grad_uz,
    const float* __restrict__ grad_phi,
    const float* __restrict__ prop_E,
    const float* __restrict__ prop_A,
    const float* __restrict__ prop_I22,
    const float* __restrict__ elem_len,
    const float* __restrict__ xhat,
    const float* __restrict__ load,
    const int*   __restrict__ conn,
    const int*   __restrict__ offs,
    const uchar2* __restrict__ rank2,
    float4* __restrict__ recA,
    uint2*  __restrict__ recB,
    Scalars* __restrict__ sc)
{
    int basee = blockIdx.x * (256 * MAIN_EPT) + threadIdx.x;
    double kin = 0.0;

    int2 ij[MAIN_EPT];
    uchar2 rk[MAIN_EPT];
    int oi[MAIN_EPT], oj[MAIN_EPT];
    bool valid[MAIN_EPT];

#pragma unroll
    for (int k = 0; k < MAIN_EPT; ++k) {
        int e = basee + k * 256;
        valid[k] = (e < N_ELEMS_C);
        if (valid[k]) ij[k] = ((const int2*)conn)[e];
    }
#pragma unroll
    for (int k = 0; k < MAIN_EPT; ++k) {
        int e = basee + k * 256;
        if (valid[k]) rk[k] = rank2[e];
    }
#pragma unroll
    for (int k = 0; k < MAIN_EPT; ++k) {
        if (valid[k]) {
            oi[k] = offs[ij[k].x];
            oj[k] = offs[ij[k].y];
        }
    }

#pragma unroll
    for (int k = 0; k < MAIN_EPT; ++k) {
        if (!valid[k]) continue;
        int e = basee + k * 256;
        size_t i = (size_t)ij[k].x;
        size_t j = (size_t)ij[k].y;

        size_t e3 = 3 * (size_t)e;
        float x0 = xhat[e3 + 0];
        float x1 = xhat[e3 + 1];
        float x2 = xhat[e3 + 2];
        float L  = elem_len[e];
        float E  = prop_E[e];
        float EA = E * prop_A[e];
        float EI = E * prop_I22[e];
        float q0 = load[e3 + 0];
        float q1 = load[e3 + 1];
        float q2 = load[e3 + 2];

        bool  par = fabsf(x1) > 0.99f;
        float r1 = par ? 0.0f : 1.0f;
        float r2 = par ? 1.0f : 0.0f;
        float z0 = x1 * r2 - x2 * r1;
        float z1 = -x0 * r2;
        float z2 =  x0 * r1;
        float zn = fmaxf(sqrtf(z0 * z0 + z1 * z1 + z2 * z2), 1e-8f);
        z0 /= zn; z1 /= zn; z2 /= zn;
        float y0 = z1 * x2 - z2 * x1;
        float y1 = z2 * x0 - z0 * x2;
        float y2 = z0 * x1 - z1 * x0;
        float yn = fmaxf(sqrtf(y0 * y0 + y1 * y1 + y2 * y2), 1e-8f);
        y0 /= yn; y1 /= yn; y2 /= yn;

        size_t i3 = 3 * i, j3 = 3 * j;
        float gux_i_ax = grad_ux[i3 + 0] * x0 + grad_ux[i3 + 1] * x1 + grad_ux[i3 + 2] * x2;
        float gux_j_ax = grad_ux[j3 + 0] * x0 + grad_ux[j3 + 1] * x1 + grad_ux[j3 + 2] * x2;
        float guz_i_ax = grad_uz[i3 + 0] * x0 + grad_uz[i3 + 1] * x1 + grad_uz[i3 + 2] * x2;
        float guz_j_ax = grad_uz[j3 + 0] * x0 + grad_uz[j3 + 1] * x1 + grad_uz[j3 + 2] * x2;
        float kap_i    = grad_phi[i3 + 0] * x0 + grad_phi[i3 + 1] * x1 + grad_phi[i3 + 2] * x2;
        float kap_j    = grad_phi[j3 + 0] * x0 + grad_phi[j3 + 1] * x1 + grad_phi[j3 + 2] * x2;

        float eps_i = x0 * gux_i_ax + x2 * guz_i_ax;
        float eps_j = x0 * gux_j_ax + x2 * guz_j_ax;
        float N_avg = 0.5f * EA * (eps_i + eps_j);
        float M_i = EI * kap_i;
        float M_j = EI * kap_j;
        float V = (M_j - M_i) / L;
        float F0 = N_avg * x0 + V * z0;
        float F1 = N_avg * x1 + V * z1;
        float F2 = N_avg * x2 + V * z2;
        float hl = 0.5f * L;
        float fe0 = q0 * hl, fe1 = q1 * hl, fe2 = q2 * hl;

        float wA = __uint_as_float(packH2(fe0, fe1));
        unsigned lii = (unsigned)(ij[k].x & (NPB - 1));
        unsigned lij = (unsigned)(ij[k].y & (NPB - 1));
        int posi = oi[k] + (int)rk[k].x;
        int posj = oj[k] + (int)rk[k].y;

        recA[posi] = make_float4(embedBits( F0, (lii >> 6) & 7u, 3),
                                 embedBits( F1, (lii >> 3) & 7u, 3),
                                 embedBits( F2, lii & 7u, 3), wA);
        recB[posi] = make_uint2(packH2(M_i * y0, M_i * y1), packH2(M_i * y2, fe2));
        recA[posj] = make_float4(embedBits(-F0, (lij >> 6) & 7u, 3),
                                 embedBits(-F1, (lij >> 3) & 7u, 3),
                                 embedBits(-F2, lij & 7u, 3), wA);
        recB[posj] = make_uint2(packH2(M_j * y0, M_j * y1), packH2(M_j * y2, fe2));

        float du_i = z0 * gux_i_ax + z2 * guz_i_ax;
        float du_j = z0 * gux_j_ax + z2 * guz_j_ax;
        float rki = phi[i] - du_i;
        float rkj = phi[j] - du_j;
        kin += (double)rki * (double)rki + (double)rkj * (double)rkj;
    }

    kin = waveSumD(kin);
    if ((threadIdx.x & 63) == 0) {
        atomicAdd(&sc->S_kin, kin);
    }
}

// ============ node pass: MLP-batched streaming + rotated-field LDS atomics ============
// 4 records per thread per iteration: all 8 loads issued before any consumption
// (quadruples outstanding memory requests -> latency-bound becomes BW-bound).
// Rotated field order keeps same-node lanes on 9 distinct LDS addresses.
__global__ __launch_bounds__(256) void node_mlp(
    const float* __restrict__ bc_disp,
    const float* __restrict__ bc_rot,
    const int*   __restrict__ offs,   // start offsets
    const float4* __restrict__ recA,
    const uint2*  __restrict__ recB,
    Scalars* __restrict__ sc)
{
    __shared__ float bins[NPB * 9];     // 18 KB
    const int n0  = blockIdx.x * NPB;
    const int cnt = min(NPB, N_NODES_C - n0);

    for (int t = threadIdx.x; t < NPB * 9; t += 256) bins[t] = 0.0f;
    __syncthreads();

    const int beg = offs[n0];
    const int end = (n0 + cnt < N_NODES_C) ? offs[n0 + cnt] : N_ENDP_C;
    const int rot = (int)(threadIdx.x % 9u);

    for (int rb = beg + threadIdx.x; rb < end; rb += 256 * RB) {
        float4 a[RB];
        uint2  b[RB];
        bool   vld[RB];
        // issue all loads first — 8 independent memory ops in flight
#pragma unroll
        for (int k = 0; k < RB; ++k) {
            int r = rb + k * 256;
            vld[k] = (r < end);
            if (vld[k]) a[k] = recA[r];
        }
#pragma unroll
        for (int k = 0; k < RB; ++k) {
            int r = rb + k * 256;
            if (vld[k]) b[k] = recB[r];
        }
#pragma unroll
        for (int k = 0; k < RB; ++k) {
            if (!vld[k]) continue;
            unsigned u0 = __float_as_uint(a[k].x);
            unsigned u1 = __float_as_uint(a[k].y);
            unsigned u2 = __float_as_uint(a[k].z);
            int li = (int)(((u0 & 7u) << 6) | ((u1 & 7u) << 3) | (u2 & 7u));
            unsigned ua = __float_as_uint(a[k].w);

            float v[9];
            v[0] = a[k].x; v[1] = a[k].y; v[2] = a[k].z;
            v[3] = lowH(b[k].x); v[4] = highH(b[k].x); v[5] = lowH(b[k].y);
            v[6] = lowH(ua);  v[7] = highH(ua);  v[8] = highH(b[k].y);

            float* bp = &bins[li * 9];
#pragma unroll
            for (int f = 0; f < 9; ++f) {
                int ff = f + rot; if (ff >= 9) ff -= 9;
                atomicAdd(bp + ff, v[ff]);
            }
        }
    }
    __syncthreads();

    double sFext = 0.0, sForce = 0.0, sMom = 0.0, sNeu = 0.0;
    int cfd = 0, cfr = 0, cpin = 0;

    for (int t = threadIdx.x; t < cnt; t += 256) {
        int n = n0 + t;
        float bd = bc_disp[n];
        float br = bc_rot[n];
        bool fd  = bd < 0.5f;
        bool fr  = br < 0.5f;
        bool pin = (bd > 0.5f) && (br < 0.5f);

        const float* bp = &bins[t * 9];
        float fi0 = bp[0], fi1 = bp[1], fi2 = bp[2];
        float m0  = bp[3], m1  = bp[4], m2  = bp[5];
        float fe0 = bp[6], fe1 = bp[7], fe2 = bp[8];

        double fesq = (double)fe0 * fe0 + (double)fe1 * fe1 + (double)fe2 * fe2;
        double s0 = (double)(fi0 + fe0);
        double s1 = (double)(fi1 + fe1);
        double s2 = (double)(fi2 + fe2);
        double fsq = s0 * s0 + s1 * s1 + s2 * s2;
        double msq = (double)m0 * m0 + (double)m1 * m1 + (double)m2 * m2;

        if (fd)  { sFext += fesq; sForce += fsq; cfd++; }
        if (fr)  { sMom += msq; cfr++; }
        if (pin) { sNeu += msq; cpin++; }
    }

    sFext  = waveSumD(sFext);
    sForce = waveSumD(sForce);
    sMom   = waveSumD(sMom);
    sNeu   = waveSumD(sNeu);
    cfd  = waveSumI(cfd);
    cfr  = waveSumI(cfr);
    cpin = waveSumI(cpin);

    if ((threadIdx.x & 63) == 0) {
        atomicAdd(&sc->S_Fext,  sFext);
        atomicAdd(&sc->S_force, sForce);
        atomicAdd(&sc->S_mom,   sMom);
        atomicAdd(&sc->S_neu,   sNeu);
        atomicAdd(&sc->n_fd,  (unsigned long long)cfd);
        atomicAdd(&sc->n_fr,  (unsigned long long)cfr);
        atomicAdd(&sc->n_pin, (unsigned long long)cpin);
    }
}

// ============ Tier B kernels (verified fallback) ============

__global__ __launch_bounds__(256) void hist_scalars(
    const int* __restrict__ conn,
    const float* __restrict__ elem_len,
    const float* __restrict__ load,
    int* __restrict__ counts,
    Scalars* __restrict__ sc)
{
    int e = blockIdx.x * blockDim.x + threadIdx.x;
    double lsum = 0.0;
    float qm = 0.0f, lm = 0.0f;
    if (e < N_ELEMS_C) {
        int2 ij = ((const int2*)conn)[e];
        atomicAdd(&counts[ij.x], 1);
        atomicAdd(&counts[ij.y], 1);
        float L = elem_len[e];
        float q0 = load[3 * (size_t)e + 0];
        float q1 = load[3 * (size_t)e + 1];
        float q2 = load[3 * (size_t)e + 2];
        lsum = (double)L;
        lm = L;
        qm = fmaxf(fmaxf(fabsf(q0), fabsf(q1)), fabsf(q2));
    }
    lsum = waveSumD(lsum);
    qm = waveMaxF(qm);
    lm = waveMaxF(lm);
    if ((threadIdx.x & 63) == 0) {
        atomicAdd(&sc->L_sum, lsum);
        atomicMax(&sc->q_max_bits, __float_as_int(qm));
        atomicMax(&sc->L_max_bits, __float_as_int(lm));
    }
}

__global__ __launch_bounds__(256) void fill_csr(
    const int* __restrict__ conn,
    const int* __restrict__ offsets,
    int* __restrict__ counts,
    int* __restrict__ eidside)
{
    int e = blockIdx.x * blockDim.x + threadIdx.x;
    if (e >= N_ELEMS_C) return;
    int2 ij = ((const int2*)conn)[e];
    int oi = atomicSub(&counts[ij.x], 1) - 1;
    eidside[offsets[ij.x] + oi] = (e << 1);
    int oj = atomicSub(&counts[ij.y], 1) - 1;
    eidside[offsets[ij.y] + oj] = (e << 1) | 1;
}

__global__ __launch_bounds__(256) void node_reduce_csr(
    const float* __restrict__ phi,
    const float* __restrict__ grad_ux,
    const float* __restrict__ grad_uz,
    const float* __restrict__ grad_phi,
    const float* __restrict__ prop_E,
    const float* __restrict__ prop_A,
    const float* __restrict__ prop_I22,
    const float* __restrict__ elem_len,
    const float* __restrict__ xhat,
    const float* __restrict__ load,
    const int*   __restrict__ conn,
    const float* __restrict__ bc_disp,
    const float* __restrict__ bc_rot,
    const int*   __restrict__ offsets,
    const int*   __restrict__ eidside,
    Scalars* __restrict__ sc)
{
    int n = blockIdx.x * blockDim.x + threadIdx.x;
    double sFext = 0.0, sForce = 0.0, sMom = 0.0, sNeu = 0.0, kin = 0.0;
    bool fd = false, fr = false, pin = false;

    if (n < N_NODES_C) {
        float bd = bc_disp[n];
        float br = bc_rot[n];
        fd  = bd < 0.5f;
        fr  = br < 0.5f;
        pin = (bd > 0.5f) && (br < 0.5f);

        float phin = phi[n];
        size_t b3 = 3 * (size_t)n;
        float ux0 = grad_ux[b3 + 0], ux1 = grad_ux[b3 + 1], ux2 = grad_ux[b3 + 2];
        float uz0 = grad_uz[b3 + 0], uz1 = grad_uz[b3 + 1], uz2 = grad_uz[b3 + 2];
        float gp0 = grad_phi[b3 + 0], gp1 = grad_phi[b3 + 1], gp2 = grad_phi[b3 + 2];

        int beg = offsets[n];
        int end = (n == N_NODES_C - 1) ? N_ENDP_C : offsets[n + 1];

        float fi0 = 0.f, fi1 = 0.f, fi2 = 0.f;
        float m0 = 0.f, m1 = 0.f, m2 = 0.f;
        float fe0 = 0.f, fe1 = 0.f, fe2 = 0.f;

        for (int k = beg; k < end; ++k) {
            int es = eidside[k];
            int e  = es >> 1;
            int s  = es & 1;
            int2 c = ((const int2*)conn)[e];
            size_t other = (size_t)(s ? c.x : c.y);

            size_t e3 = 3 * (size_t)e;
            float x0 = xhat[e3 + 0];
            float x1 = xhat[e3 + 1];
            float x2 = xhat[e3 + 2];
            float L  = elem_len[e];
            float E  = prop_E[e];
            float EA = E * prop_A[e];
            float EI = E * prop_I22[e];
            float q0 = load[e3 + 0];
            float q1 = load[e3 + 1];
            float q2 = load[e3 + 2];

            bool  par = fabsf(x1) > 0.99f;
            float r1 = par ? 0.0f : 1.0f;
            float r2 = par ? 1.0f : 0.0f;
            float z0 = x1 * r2 - x2 * r1;
            float z1 = -x0 * r2;
            float z2 =  x0 * r1;
            float zn = fmaxf(sqrtf(z0 * z0 + z1 * z1 + z2 * z2), 1e-8f);
            z0 /= zn; z1 /= zn; z2 /= zn;
            float y0 = z1 * x2 - z2 * x1;
            float y1 = z2 * x0 - z0 * x2;
            float y2 = z0 * x1 - z1 * x0;
            float yn = fmaxf(sqrtf(y0 * y0 + y1 * y1 + y2 * y2), 1e-8f);
            y0 /= yn; y1 /= yn; y2 /= yn;

            float own_ux_ax = ux0 * x0 + ux1 * x1 + ux2 * x2;
            float own_uz_ax = uz0 * x0 + uz1 * x1 + uz2 * x2;
            float kap_own   = gp0 * x0 + gp1 * x1 + gp2 * x2;

            size_t o3 = 3 * other;
            float oth_ux_ax = grad_ux[o3 + 0] * x0 + grad_ux[o3 + 1] * x1 + grad_ux[o3 + 2] * x2;
            float oth_uz_ax = grad_uz[o3 + 0] * x0 + grad_uz[o3 + 1] * x1 + grad_uz[o3 + 2] * x2;
            float kap_oth   = grad_phi[o3 + 0] * x0 + grad_phi[o3 + 1] * x1 + grad_phi[o3 + 2] * x2;

            float eps_own = x0 * own_ux_ax + x2 * own_uz_ax;
            float eps_oth = x0 * oth_ux_ax + x2 * oth_uz_ax;
            float N_avg = 0.5f * EA * (eps_own + eps_oth);
            float M_own = EI * kap_own;
            float M_oth = EI * kap_oth;
            float Vz = (M_oth - M_own) / L;
            float t = s ? -1.0f : 1.0f;

            fi0 += t * N_avg * x0 + Vz * z0;
            fi1 += t * N_avg * x1 + Vz * z1;
            fi2 += t * N_avg * x2 + Vz * z2;
            m0  += M_own * y0;
            m1  += M_own * y1;
            m2  += M_own * y2;
            float hl = 0.5f * L;
            fe0 += q0 * hl;
            fe1 += q1 * hl;
            fe2 += q2 * hl;

            float du = z0 * own_ux_ax + z2 * own_uz_ax;
            float rk = phin - du;
            kin += (double)rk * (double)rk;
        }

        double fesq = (double)fe0 * fe0 + (double)fe1 * fe1 + (double)fe2 * fe2;
        double s0 = (double)(fi0 + fe0);
        double s1 = (double)(fi1 + fe1);
        double s2 = (double)(fi2 + fe2);
        double fsq = s0 * s0 + s1 * s1 + s2 * s2;
        double msq = (double)m0 * m0 + (double)m1 * m1 + (double)m2 * m2;

        if (fd)  { sFext = fesq; sForce = fsq; }
        if (fr)  { sMom = msq; }
        if (pin) { sNeu = msq; }
    }

    unsigned long long cfd  = __popcll(__ballot(fd));
    unsigned long long cfr  = __popcll(__ballot(fr));
    unsigned long long cpin = __popcll(__ballot(pin));

    sFext  = waveSumD(sFext);
    sForce = waveSumD(sForce);
    sMom   = waveSumD(sMom);
    sNeu   = waveSumD(sNeu);
    kin    = waveSumD(kin);

    if ((threadIdx.x & 63) == 0) {
        atomicAdd(&sc->S_Fext,  sFext);
        atomicAdd(&sc->S_force, sForce);
        atomicAdd(&sc->S_mom,   sMom);
        atomicAdd(&sc->S_neu,   sNeu);
        atomicAdd(&sc->S_kin,   kin);
        atomicAdd(&sc->n_fd,  cfd);
        atomicAdd(&sc->n_fr,  cfr);
        atomicAdd(&sc->n_pin, cpin);
    }
}

// ============ finalize ============

__global__ void finalize_kernel(const Scalars* __restrict__ sc, float* __restrict__ out)
{
    double n_fd = (double)(sc->n_fd > 0ull ? sc->n_fd : 1ull);
    double n_fr = (double)(sc->n_fr > 0ull ? sc->n_fr : 1ull);

    double F_char = sqrt(sc->S_Fext / (3.0 * n_fd));
    if (F_char < 1.0) F_char = 1.0;

    double q_max = (double)__int_as_float(sc->q_max_bits);
    if (q_max < 1.0) q_max = 1.0;
    double L_max = (double)__int_as_float(sc->L_max_bits);
    double M_char = q_max * L_max * sc->L_sum / 8.0;
    if (M_char < 1.0) M_char = 1.0;

    double L_force  = sc->S_force / (3.0 * n_fd) / (F_char * F_char);
    double L_moment = sc->S_mom   / (3.0 * n_fr) / (M_char * M_char);
    double L_neu = 0.0;
    if (sc->n_pin > 0ull) {
        L_neu = sc->S_neu / (3.0 * (double)sc->n_pin) / (M_char * M_char);
    }
    double L_kin = 0.5 * sc->S_kin / (double)N_ELEMS_C;

    out[0] = (float)(1.0 * L_force + 1.0 * L_moment + 1.0 * L_neu + 0.1 * L_kin);
}

// ============ host ============

extern "C" void kernel_launch(void* const* d_in, const int* in_sizes, int n_in,
                              void* d_out, int out_size, void* d_ws, size_t ws_size,
                              hipStream_t stream) {
    const float* phi       = (const float*)d_in[0];
    const float* grad_ux   = (const float*)d_in[1];
    const float* grad_uz   = (const float*)d_in[2];
    const float* grad_phi  = (const float*)d_in[3];
    const float* prop_E    = (const float*)d_in[4];
    const float* prop_A    = (const float*)d_in[5];
    const float* prop_I22  = (const float*)d_in[6];
    const float* elem_len  = (const float*)d_in[7];
    const float* elem_dir  = (const float*)d_in[8];
    const float* elem_load = (const float*)d_in[9];
    const float* bc_disp   = (const float*)d_in[10];
    const float* bc_rot    = (const float*)d_in[11];
    const int*   conn      = (const int*)d_in[12];

    const size_t HDR     = 65536;                      // sc + tileSums
    const size_t szNode  = (size_t)N_NODES_C * 4;      //   4 MB (offsets / counts)
    const size_t szRank  = (size_t)N_ELEMS_C * 2;      //   8 MB (uchar2/elem)
    const size_t szPack  = (size_t)N_NODES_C * 40;     //  40 MB (10 floats tight)
    const size_t szRecA  = (size_t)N_ENDP_C * 16;      // 128 MB
    const size_t szRecB  = (size_t)N_ENDP_C * 8;       //  64 MB

    const size_t needRp = HDR + szNode + szRank + szPack + szRecA + szRecB; // ~244.1 MB
    const size_t needRu = HDR + szNode + szRank + szRecA + szRecB;          // ~204.1 MB

    const int egrid = (N_ELEMS_C + 255) / 256;
    const int ngrid = (N_NODES_C + 255) / 256;
    const int hgrid = (N_ELEMS_C + 256 * HIST_EPT - 1) / (256 * HIST_EPT);
    const int mgrid = (N_ELEMS_C + 256 * MAIN_EPT - 1) / (256 * MAIN_EPT);

    if (ws_size >= needRu) {
        const bool packed = (ws_size >= needRp);

        char* p = (char*)d_ws;
        Scalars* sc   = (Scalars*)p;
        int* tileSums = (int*)(p + 128);
        p += HDR;
        int* offsets  = (int*)p;      p += szNode;
        uchar2* rank2 = (uchar2*)p;   p += szRank;
        float2* pack  = (float2*)p;   if (packed) p += szPack;
        float4* recA  = (float4*)p;   p += szRecA;
        uint2*  recB  = (uint2*)p;
        int* counts   = (int*)recA;   // aliased: dead after scan_within, before recA writes

        hipMemsetAsync(sc, 0, 128, stream);
        hipMemsetAsync(counts, 0, szNode, stream);

        if (packed) {
            pack_nodes10<<<ngrid, 256, 0, stream>>>(phi, grad_ux, grad_uz, grad_phi, pack);
        }
        hist_rank<<<hgrid, 256, 0, stream>>>(conn, elem_len, elem_load, counts, rank2, sc);
        tile_sum<<<N_TILES, 256, 0, stream>>>(counts, tileSums);
        scan_tiles<<<1, 1024, 0, stream>>>(tileSums);
        scan_within<<<N_TILES, 256, 0, stream>>>(counts, tileSums, offsets);
        if (packed) {
            main_rank_p<<<mgrid, 256, 0, stream>>>(
                pack, prop_E, prop_A, prop_I22, elem_len, elem_dir, elem_load, conn,
                offsets, rank2, recA, recB, sc);
        } else {
            main_rank_u<<<mgrid, 256, 0, stream>>>(
                phi, grad_ux, grad_uz, grad_phi,
                prop_E, prop_A, prop_I22, elem_len, elem_dir, elem_load, conn,
                offsets, rank2, recA, recB, sc);
        }
        node_mlp<<<N_NBLOCKS, 256, 0, stream>>>(bc_disp, bc_rot, offsets, recA, recB, sc);
        finalize_kernel<<<1, 1, 0, stream>>>(sc, (float*)d_out);
    } else {
        // ---- Tier B (verified fallback) ----
        char* p = (char*)d_ws;
        int* counts   = (int*)p;      p += szNode;
        Scalars* sc   = (Scalars*)p;  p += 128;
        int* offsets  = (int*)p;      p += szNode;
        int* tileSums = (int*)p;      p += 4096;
        int* eidside  = (int*)p;

        hipMemsetAsync(counts, 0, szNode + 128, stream);
        hist_scalars<<<egrid, 256, 0, stream>>>(conn, elem_len, elem_load, counts, sc);
        tile_sum<<<N_TILES, 256, 0, stream>>>(counts, tileSums);
        scan_tiles<<<1, 1024, 0, stream>>>(tileSums);
        scan_within<<<N_TILES, 256, 0, stream>>>(counts, tileSums, offsets);
        fill_csr<<<egrid, 256, 0, stream>>>(conn, offsets, counts, eidside);
        node_reduce_csr<<<ngrid, 256, 0, stream>>>(
            phi, grad_ux, grad_uz, grad_phi,
            prop_E, prop_A, prop_I22, elem_len, elem_dir, elem_load, conn,
            bc_disp, bc_rot, offsets, eidside, sc);
        finalize_kernel<<<1, 1, 0, stream>>>(sc, (float*)d_out);
    }
}

// Round 8
// 1497.402 us; speedup vs baseline: 1.2548x; 1.2498x over previous
//
#include <hip/hip_runtime.h>
#include <hip/hip_fp16.h>

#define N_NODES_C 1000000
#define N_ELEMS_C 4000000
#define N_ENDP_C  (2 * N_ELEMS_C)
#define TILE 1024
#define N_TILES ((N_NODES_C + TILE - 1) / TILE)   // 977
#define HIST_EPT 8
#define MAIN_EPT 4
#define NPB 512                                    // nodes per block in node_mlp
#define N_NBLOCKS ((N_NODES_C + NPB - 1) / NPB)    // 1954
#define RB 4                                       // records per thread per iter
#define HGRID ((N_ELEMS_C + 256 * HIST_EPT - 1) / (256 * HIST_EPT))  // 1954
#define MGRID ((N_ELEMS_C + 256 * MAIN_EPT - 1) / (256 * MAIN_EPT))  // 3907

struct Scalars {
    double S_kin;
    double L_sum;
    double S_Fext;
    double S_force;
    double S_mom;
    double S_neu;
    unsigned long long n_fd;
    unsigned long long n_fr;
    unsigned long long n_pin;
    int q_max_bits;
    int L_max_bits;
};

struct HistP { double lsum; float qm, lm; };                         // 16 B
struct NodeP { double fext, force, mom, neu; int fd, fr, pin, pad; };// 48 B

__device__ __forceinline__ double waveSumD(double v) {
    for (int off = 32; off > 0; off >>= 1) v += __shfl_down(v, off, 64);
    return v;
}
__device__ __forceinline__ float waveMaxF(float v) {
    for (int off = 32; off > 0; off >>= 1) v = fmaxf(v, __shfl_down(v, off, 64));
    return v;
}
__device__ __forceinline__ int waveSumI(int v) {
    for (int off = 32; off > 0; off >>= 1) v += __shfl_down(v, off, 64);
    return v;
}
__device__ __forceinline__ unsigned packH2(float a, float b) {
    return (unsigned)__half_as_ushort(__float2half(a)) |
           ((unsigned)__half_as_ushort(__float2half(b)) << 16);
}
__device__ __forceinline__ float lowH(unsigned u)  { return __half2float(__ushort_as_half((unsigned short)(u & 0xFFFFu))); }
__device__ __forceinline__ float highH(unsigned u) { return __half2float(__ushort_as_half((unsigned short)(u >> 16))); }
// embed nb low bits into float mantissa (rel err <= 2^-(23-nb), harmless)
__device__ __forceinline__ float embedBits(float f, unsigned bits, unsigned nb) {
    unsigned u = __float_as_uint(f);
    u = (u & ~((1u << nb) - 1u)) | bits;
    return __uint_as_float(u);
}

// ============ node-data pack: 10 floats tight (40B) per node ============
__global__ __launch_bounds__(256) void pack_nodes10(
    const float* __restrict__ phi,
    const float* __restrict__ grad_ux,
    const float* __restrict__ grad_uz,
    const float* __restrict__ grad_phi,
    float2* __restrict__ pack)          // 5 float2 per node
{
    int n = blockIdx.x * blockDim.x + threadIdx.x;
    if (n >= N_NODES_C) return;
    size_t n3 = 3 * (size_t)n;
    float ux0 = grad_ux[n3 + 0], ux1 = grad_ux[n3 + 1], ux2 = grad_ux[n3 + 2];
    float uz0 = grad_uz[n3 + 0], uz1 = grad_uz[n3 + 1], uz2 = grad_uz[n3 + 2];
    float gp0 = grad_phi[n3 + 0], gp1 = grad_phi[n3 + 1], gp2 = grad_phi[n3 + 2];
    float ph  = phi[n];
    float2* P = pack + (size_t)n * 5;
    P[0] = make_float2(ux0, ux1);
    P[1] = make_float2(ux2, uz0);
    P[2] = make_float2(uz1, uz2);
    P[3] = make_float2(gp0, gp1);
    P[4] = make_float2(gp2, ph);
}

// ============ hist + RANK (returning atomicAdd); partials or atomic finish ============
__global__ __launch_bounds__(256) void hist_rank(
    const int* __restrict__ conn,
    const float* __restrict__ elem_len,
    const float* __restrict__ load,
    int* __restrict__ counts,
    uchar2* __restrict__ rank2,
    Scalars* __restrict__ sc,
    HistP* __restrict__ hp)            // non-null => per-block partials, no scalar atomics
{
    int base = blockIdx.x * (256 * HIST_EPT) + threadIdx.x;
    double lsum = 0.0;
    float qm = 0.0f, lm = 0.0f;

    int2 ij[HIST_EPT];
    int ri[HIST_EPT], rj[HIST_EPT];
    bool valid[HIST_EPT];
#pragma unroll
    for (int k = 0; k < HIST_EPT; ++k) {
        int e = base + k * 256;
        valid[k] = (e < N_ELEMS_C);
        if (valid[k]) ij[k] = ((const int2*)conn)[e];
    }
    // 16 independent returning atomics in flight (scattered over 1M lines)
#pragma unroll
    for (int k = 0; k < HIST_EPT; ++k) {
        if (valid[k]) {
            ri[k] = atomicAdd(&counts[ij[k].x], 1);
            rj[k] = atomicAdd(&counts[ij[k].y], 1);
        }
    }
#pragma unroll
    for (int k = 0; k < HIST_EPT; ++k) {
        int e = base + k * 256;
        if (valid[k]) {
            rank2[e] = make_uchar2((unsigned char)min(ri[k], 255),
                                   (unsigned char)min(rj[k], 255));
        }
    }
#pragma unroll
    for (int k = 0; k < HIST_EPT; ++k) {
        int e = base + k * 256;
        if (valid[k]) {
            float L = elem_len[e];
            float q0 = load[3 * (size_t)e + 0];
            float q1 = load[3 * (size_t)e + 1];
            float q2 = load[3 * (size_t)e + 2];
            lsum += (double)L;
            lm = fmaxf(lm, L);
            qm = fmaxf(qm, fmaxf(fmaxf(fabsf(q0), fabsf(q1)), fabsf(q2)));
        }
    }

    lsum = waveSumD(lsum);
    qm = waveMaxF(qm);
    lm = waveMaxF(lm);
    if (hp) {
        __shared__ double sl[4];
        __shared__ float sq[4], sm[4];
        int w = threadIdx.x >> 6;
        if ((threadIdx.x & 63) == 0) { sl[w] = lsum; sq[w] = qm; sm[w] = lm; }
        __syncthreads();
        if (threadIdx.x == 0) {
            HistP h;
            h.lsum = sl[0] + sl[1] + sl[2] + sl[3];
            h.qm = fmaxf(fmaxf(sq[0], sq[1]), fmaxf(sq[2], sq[3]));
            h.lm = fmaxf(fmaxf(sm[0], sm[1]), fmaxf(sm[2], sm[3]));
            hp[blockIdx.x] = h;
        }
    } else if ((threadIdx.x & 63) == 0) {
        atomicAdd(&sc->L_sum, lsum);
        atomicMax(&sc->q_max_bits, __float_as_int(qm));
        atomicMax(&sc->L_max_bits, __float_as_int(lm));
    }
}

// ============ scan kernels (verified) ============

__global__ __launch_bounds__(256) void tile_sum(
    const int* __restrict__ counts, int* __restrict__ tileSums)
{
    int tile = blockIdx.x;
    int base = tile * TILE;
    int s = 0;
    for (int k = threadIdx.x; k < TILE; k += 256) {
        int idx = base + k;
        s += (idx < N_NODES_C) ? counts[idx] : 0;
    }
    s = waveSumI(s);
    __shared__ int sh[4];
    if ((threadIdx.x & 63) == 0) sh[threadIdx.x >> 6] = s;
    __syncthreads();
    if (threadIdx.x == 0) tileSums[tile] = sh[0] + sh[1] + sh[2] + sh[3];
}

__global__ __launch_bounds__(1024) void scan_tiles(int* __restrict__ tileSums)
{
    __shared__ int sh[1024];
    int t = threadIdx.x;
    int v = (t < N_TILES) ? tileSums[t] : 0;
    sh[t] = v;
    __syncthreads();
    for (int s = 1; s < 1024; s <<= 1) {
        int a = (t >= s) ? sh[t - s] : 0;
        __syncthreads();
        sh[t] += a;
        __syncthreads();
    }
    if (t < N_TILES) tileSums[t] = sh[t] - v;   // exclusive over tiles
}

// EXCLUSIVE scan -> offsets (start offsets)
__global__ __launch_bounds__(256) void scan_within(
    const int* __restrict__ counts, const int* __restrict__ tileSums,
    int* __restrict__ offsets)
{
    int tile = blockIdx.x;
    int base = tile * TILE;
    int t = threadIdx.x;
    int i0 = base + t * 4;
    int c0 = (i0 + 0 < N_NODES_C) ? counts[i0 + 0] : 0;
    int c1 = (i0 + 1 < N_NODES_C) ? counts[i0 + 1] : 0;
    int c2 = (i0 + 2 < N_NODES_C) ? counts[i0 + 2] : 0;
    int c3 = (i0 + 3 < N_NODES_C) ? counts[i0 + 3] : 0;
    int tsum = c0 + c1 + c2 + c3;
    __shared__ int sh[256];
    sh[t] = tsum;
    __syncthreads();
    for (int s = 1; s < 256; s <<= 1) {
        int a = (t >= s) ? sh[t - s] : 0;
        __syncthreads();
        sh[t] += a;
        __syncthreads();
    }
    int run = tileSums[tile] + (sh[t] - tsum);
    if (i0 + 0 < N_NODES_C) offsets[i0 + 0] = run; run += c0;
    if (i0 + 1 < N_NODES_C) offsets[i0 + 1] = run; run += c1;
    if (i0 + 2 < N_NODES_C) offsets[i0 + 2] = run; run += c2;
    if (i0 + 3 < N_NODES_C) offsets[i0 + 3] = run;
}

// ============ main pass, PACKED gathers, NO atomics (pos = offs + rank) ============
__global__ __launch_bounds__(256) void main_rank_p(
    const float2* __restrict__ pack,
    const float* __restrict__ prop_E,
    const float* __restrict__ prop_A,
    const float* __restrict__ prop_I22,
    const float* __restrict__ elem_len,
    const float* __restrict__ xhat,
    const float* __restrict__ load,
    const int*   __restrict__ conn,
    const int*   __restrict__ offs,
    const uchar2* __restrict__ rank2,
    float4* __restrict__ recA,
    uint2*  __restrict__ recB,
    Scalars* __restrict__ sc,
    double* __restrict__ mp)           // non-null => per-block partials
{
    int basee = blockIdx.x * (256 * MAIN_EPT) + threadIdx.x;
    double kin = 0.0;

    int2 ij[MAIN_EPT];
    uchar2 rk[MAIN_EPT];
    int oi[MAIN_EPT], oj[MAIN_EPT];
    bool valid[MAIN_EPT];

#pragma unroll
    for (int k = 0; k < MAIN_EPT; ++k) {
        int e = basee + k * 256;
        valid[k] = (e < N_ELEMS_C);
        if (valid[k]) ij[k] = ((const int2*)conn)[e];
    }
#pragma unroll
    for (int k = 0; k < MAIN_EPT; ++k) {
        int e = basee + k * 256;
        if (valid[k]) rk[k] = rank2[e];
    }
#pragma unroll
    for (int k = 0; k < MAIN_EPT; ++k) {
        if (valid[k]) {
            oi[k] = offs[ij[k].x];
            oj[k] = offs[ij[k].y];
        }
    }

#pragma unroll
    for (int k = 0; k < MAIN_EPT; ++k) {
        if (!valid[k]) continue;
        int e = basee + k * 256;
        size_t i = (size_t)ij[k].x;
        size_t j = (size_t)ij[k].y;

        const float2* Pi = pack + i * 5;
        const float2* Pj = pack + j * 5;
        float2 i0 = Pi[0], i1 = Pi[1], i2 = Pi[2], i3 = Pi[3], i4 = Pi[4];
        float2 j0 = Pj[0], j1 = Pj[1], j2 = Pj[2], j3 = Pj[3], j4 = Pj[4];

        size_t e3 = 3 * (size_t)e;
        float x0 = xhat[e3 + 0];
        float x1 = xhat[e3 + 1];
        float x2 = xhat[e3 + 2];
        float L  = elem_len[e];
        float E  = prop_E[e];
        float EA = E * prop_A[e];
        float EI = E * prop_I22[e];
        float q0 = load[e3 + 0];
        float q1 = load[e3 + 1];
        float q2 = load[e3 + 2];

        bool  par = fabsf(x1) > 0.99f;
        float r1 = par ? 0.0f : 1.0f;
        float r2 = par ? 1.0f : 0.0f;
        float z0 = x1 * r2 - x2 * r1;
        float z1 = -x0 * r2;
        float z2 =  x0 * r1;
        float zn = fmaxf(sqrtf(z0 * z0 + z1 * z1 + z2 * z2), 1e-8f);
        z0 /= zn; z1 /= zn; z2 /= zn;
        float y0 = z1 * x2 - z2 * x1;
        float y1 = z2 * x0 - z0 * x2;
        float y2 = z0 * x1 - z1 * x0;
        float yn = fmaxf(sqrtf(y0 * y0 + y1 * y1 + y2 * y2), 1e-8f);
        y0 /= yn; y1 /= yn; y2 /= yn;

        float gux_i_ax = i0.x * x0 + i0.y * x1 + i1.x * x2;
        float guz_i_ax = i1.y * x0 + i2.x * x1 + i2.y * x2;
        float kap_i    = i3.x * x0 + i3.y * x1 + i4.x * x2;
        float gux_j_ax = j0.x * x0 + j0.y * x1 + j1.x * x2;
        float guz_j_ax = j1.y * x0 + j2.x * x1 + j2.y * x2;
        float kap_j    = j3.x * x0 + j3.y * x1 + j4.x * x2;

        float eps_i = x0 * gux_i_ax + x2 * guz_i_ax;
        float eps_j = x0 * gux_j_ax + x2 * guz_j_ax;
        float N_avg = 0.5f * EA * (eps_i + eps_j);
        float M_i = EI * kap_i;
        float M_j = EI * kap_j;
        float V = (M_j - M_i) / L;
        float F0 = N_avg * x0 + V * z0;
        float F1 = N_avg * x1 + V * z1;
        float F2 = N_avg * x2 + V * z2;
        float hl = 0.5f * L;
        float fe0 = q0 * hl, fe1 = q1 * hl, fe2 = q2 * hl;

        float wA = __uint_as_float(packH2(fe0, fe1));
        unsigned lii = (unsigned)(ij[k].x & (NPB - 1));
        unsigned lij = (unsigned)(ij[k].y & (NPB - 1));
        int posi = oi[k] + (int)rk[k].x;
        int posj = oj[k] + (int)rk[k].y;

        recA[posi] = make_float4(embedBits( F0, (lii >> 6) & 7u, 3),
                                 embedBits( F1, (lii >> 3) & 7u, 3),
                                 embedBits( F2, lii & 7u, 3), wA);
        recB[posi] = make_uint2(packH2(M_i * y0, M_i * y1), packH2(M_i * y2, fe2));
        recA[posj] = make_float4(embedBits(-F0, (lij >> 6) & 7u, 3),
                                 embedBits(-F1, (lij >> 3) & 7u, 3),
                                 embedBits(-F2, lij & 7u, 3), wA);
        recB[posj] = make_uint2(packH2(M_j * y0, M_j * y1), packH2(M_j * y2, fe2));

        float du_i = z0 * gux_i_ax + z2 * guz_i_ax;
        float du_j = z0 * gux_j_ax + z2 * guz_j_ax;
        float rki = i4.y - du_i;
        float rkj = j4.y - du_j;
        kin += (double)rki * (double)rki + (double)rkj * (double)rkj;
    }

    kin = waveSumD(kin);
    if (mp) {
        __shared__ double sk[4];
        if ((threadIdx.x & 63) == 0) sk[threadIdx.x >> 6] = kin;
        __syncthreads();
        if (threadIdx.x == 0) mp[blockIdx.x] = sk[0] + sk[1] + sk[2] + sk[3];
    } else if ((threadIdx.x & 63) == 0) {
        atomicAdd(&sc->S_kin, kin);
    }
}

// ============ main pass, UNPACKED gathers (fallback when pack doesn't fit) ============
__global__ __launch_bounds__(256) void main_rank_u(
    const float* __restrict__ phi,
    const float* __restrict__ grad_ux,
    const float* __restrict__ grad_uz,
    const float* __restrict__ grad_phi,
    const float* __restrict__ prop_E,
    const float* __restrict__ prop_A,
    const float* __restrict__ prop_I22,
    const float* __restrict__ elem_len,
    const float* __restrict__ xhat,
    const float* __restrict__ load,
    const int*   __restrict__ conn,
    const int*   __restrict__ offs,
    const uchar2* __restrict__ rank2,
    float4* __restrict__ recA,
    uint2*  __restrict__ recB,
    Scalars* __restrict__ sc,
    double* __restrict__ mp)
{
    int basee = blockIdx.x * (256 * MAIN_EPT) + threadIdx.x;
    double kin = 0.0;

    int2 ij[MAIN_EPT];
    uchar2 rk[MAIN_EPT];
    int oi[MAIN_EPT], oj[MAIN_EPT];
    bool valid[MAIN_EPT];

#pragma unroll
    for (int k = 0; k < MAIN_EPT; ++k) {
        int e = basee + k * 256;
        valid[k] = (e < N_ELEMS_C);
        if (valid[k]) ij[k] = ((const int2*)conn)[e];
    }
#pragma unroll
    for (int k = 0; k < MAIN_EPT; ++k) {
        int e = basee + k * 256;
        if (valid[k]) rk[k] = rank2[e];
    }
#pragma unroll
    for (int k = 0; k < MAIN_EPT; ++k) {
        if (valid[k]) {
            oi[k] = offs[ij[k].x];
            oj[k] = offs[ij[k].y];
        }
    }

#pragma unroll
    for (int k = 0; k < MAIN_EPT; ++k) {
        if (!valid[k]) continue;
        int e = basee + k * 256;
        size_t i = (size_t)ij[k].x;
        size_t j = (size_t)ij[k].y;

        size_t e3 = 3 * (size_t)e;
        float x0 = xhat[e3 + 0];
        float x1 = xhat[e3 + 1];
        float x2 = xhat[e3 + 2];
        float L  = elem_len[e];
        float E  = prop_E[e];
        float EA = E * prop_A[e];
        float EI = E * prop_I22[e];
        float q0 = load[e3 + 0];
        float q1 = load[e3 + 1];
        float q2 = load[e3 + 2];

        bool  par = fabsf(x1) > 0.99f;
        float r1 = par ? 0.0f : 1.0f;
        float r2 = par ? 1.0f : 0.0f;
        float z0 = x1 * r2 - x2 * r1;
        float z1 = -x0 * r2;
        float z2 =  x0 * r1;
        float zn = fmaxf(sqrtf(z0 * z0 + z1 * z1 + z2 * z2), 1e-8f);
        z0 /= zn; z1 /= zn; z2 /= zn;
        float y0 = z1 * x2 - z2 * x1;
        float y1 = z2 * x0 - z0 * x2;
        float y2 = z0 * x1 - z1 * x0;
        float yn = fmaxf(sqrtf(y0 * y0 + y1 * y1 + y2 * y2), 1e-8f);
        y0 /= yn; y1 /= yn; y2 /= yn;

        size_t i3 = 3 * i, j3 = 3 * j;
        float gux_i_ax = grad_ux[i3 + 0] * x0 + grad_ux[i3 + 1] * x1 + grad_ux[i3 + 2] * x2;
        float gux_j_ax = grad_ux[j3 + 0] * x0 + grad_ux[j3 + 1] * x1 + grad_ux[j3 + 2] * x2;
        float guz_i_ax = grad_uz[i3 + 0] * x0 + grad_uz[i3 + 1] * x1 + grad_uz[i3 + 2] * x2;
        float guz_j_ax = grad_uz[j3 + 0] * x0 + grad_uz[j3 + 1] * x1 + grad_uz[j3 + 2] * x2;
        float kap_i    = grad_phi[i3 + 0] * x0 + grad_phi[i3 + 1] * x1 + grad_phi[i3 + 2] * x2;
        float kap_j    = grad_phi[j3 + 0] * x0 + grad_phi[j3 + 1] * x1 + grad_phi[j3 + 2] * x2;

        float eps_i = x0 * gux_i_ax + x2 * guz_i_ax;
        float eps_j = x0 * gux_j_ax + x2 * guz_j_ax;
        float N_avg = 0.5f * EA * (eps_i + eps_j);
        float M_i = EI * kap_i;
        float M_j = EI * kap_j;
        float V = (M_j - M_i) / L;
        float F0 = N_avg * x0 + V * z0;
        float F1 = N_avg * x1 + V * z1;
        float F2 = N_avg * x2 + V * z2;
        float hl = 0.5f * L;
        float fe0 = q0 * hl, fe1 = q1 * hl, fe2 = q2 * hl;

        float wA = __uint_as_float(packH2(fe0, fe1));
        unsigned lii = (unsigned)(ij[k].x & (NPB - 1));
        unsigned lij = (unsigned)(ij[k].y & (NPB - 1));
        int posi = oi[k] + (int)rk[k].x;
        int posj = oj[k] + (int)rk[k].y;

        recA[posi] = make_float4(embedBits( F0, (lii >> 6) & 7u, 3),
                                 embedBits( F1, (lii >> 3) & 7u, 3),
                                 embedBits( F2, lii & 7u, 3), wA);
        recB[posi] = make_uint2(packH2(M_i * y0, M_i * y1), packH2(M_i * y2, fe2));
        recA[posj] = make_float4(embedBits(-F0, (lij >> 6) & 7u, 3),
                                 embedBits(-F1, (lij >> 3) & 7u, 3),
                                 embedBits(-F2, lij & 7u, 3), wA);
        recB[posj] = make_uint2(packH2(M_j * y0, M_j * y1), packH2(M_j * y2, fe2));

        float du_i = z0 * gux_i_ax + z2 * guz_i_ax;
        float du_j = z0 * gux_j_ax + z2 * guz_j_ax;
        float rki = phi[i] - du_i;
        float rkj = phi[j] - du_j;
        kin += (double)rki * (double)rki + (double)rkj * (double)rkj;
    }

    kin = waveSumD(kin);
    if (mp) {
        __shared__ double sk[4];
        if ((threadIdx.x & 63) == 0) sk[threadIdx.x >> 6] = kin;
        __syncthreads();
        if (threadIdx.x == 0) mp[blockIdx.x] = sk[0] + sk[1] + sk[2] + sk[3];
    } else if ((threadIdx.x & 63) == 0) {
        atomicAdd(&sc->S_kin, kin);
    }
}

// ============ node pass: MLP-batched streaming + rotated-field LDS atomics ============
__global__ __launch_bounds__(256) void node_mlp(
    const float* __restrict__ bc_disp,
    const float* __restrict__ bc_rot,
    const int*   __restrict__ offs,   // start offsets
    const float4* __restrict__ recA,
    const uint2*  __restrict__ recB,
    Scalars* __restrict__ sc,
    NodeP* __restrict__ np)           // non-null => per-block partials
{
    __shared__ float bins[NPB * 9];     // 18 KB
    const int n0  = blockIdx.x * NPB;
    const int cnt = min(NPB, N_NODES_C - n0);

    for (int t = threadIdx.x; t < NPB * 9; t += 256) bins[t] = 0.0f;
    __syncthreads();

    const int beg = offs[n0];
    const int end = (n0 + cnt < N_NODES_C) ? offs[n0 + cnt] : N_ENDP_C;
    const int rot = (int)(threadIdx.x % 9u);

    for (int rb = beg + threadIdx.x; rb < end; rb += 256 * RB) {
        float4 a[RB];
        uint2  b[RB];
        bool   vld[RB];
#pragma unroll
        for (int k = 0; k < RB; ++k) {
            int r = rb + k * 256;
            vld[k] = (r < end);
            if (vld[k]) a[k] = recA[r];
        }
#pragma unroll
        for (int k = 0; k < RB; ++k) {
            int r = rb + k * 256;
            if (vld[k]) b[k] = recB[r];
        }
#pragma unroll
        for (int k = 0; k < RB; ++k) {
            if (!vld[k]) continue;
            unsigned u0 = __float_as_uint(a[k].x);
            unsigned u1 = __float_as_uint(a[k].y);
            unsigned u2 = __float_as_uint(a[k].z);
            int li = (int)(((u0 & 7u) << 6) | ((u1 & 7u) << 3) | (u2 & 7u));
            unsigned ua = __float_as_uint(a[k].w);

            float v[9];
            v[0] = a[k].x; v[1] = a[k].y; v[2] = a[k].z;
            v[3] = lowH(b[k].x); v[4] = highH(b[k].x); v[5] = lowH(b[k].y);
            v[6] = lowH(ua);  v[7] = highH(ua);  v[8] = highH(b[k].y);

            float* bp = &bins[li * 9];
#pragma unroll
            for (int f = 0; f < 9; ++f) {
                int ff = f + rot; if (ff >= 9) ff -= 9;
                atomicAdd(bp + ff, v[ff]);
            }
        }
    }
    __syncthreads();

    double sFext = 0.0, sForce = 0.0, sMom = 0.0, sNeu = 0.0;
    int cfd = 0, cfr = 0, cpin = 0;

    for (int t = threadIdx.x; t < cnt; t += 256) {
        int n = n0 + t;
        float bd = bc_disp[n];
        float br = bc_rot[n];
        bool fd  = bd < 0.5f;
        bool fr  = br < 0.5f;
        bool pin = (bd > 0.5f) && (br < 0.5f);

        const float* bp = &bins[t * 9];
        float fi0 = bp[0], fi1 = bp[1], fi2 = bp[2];
        float m0  = bp[3], m1  = bp[4], m2  = bp[5];
        float fe0 = bp[6], fe1 = bp[7], fe2 = bp[8];

        double fesq = (double)fe0 * fe0 + (double)fe1 * fe1 + (double)fe2 * fe2;
        double s0 = (double)(fi0 + fe0);
        double s1 = (double)(fi1 + fe1);
        double s2 = (double)(fi2 + fe2);
        double fsq = s0 * s0 + s1 * s1 + s2 * s2;
        double msq = (double)m0 * m0 + (double)m1 * m1 + (double)m2 * m2;

        if (fd)  { sFext += fesq; sForce += fsq; cfd++; }
        if (fr)  { sMom += msq; cfr++; }
        if (pin) { sNeu += msq; cpin++; }
    }

    sFext  = waveSumD(sFext);
    sForce = waveSumD(sForce);
    sMom   = waveSumD(sMom);
    sNeu   = waveSumD(sNeu);
    cfd  = waveSumI(cfd);
    cfr  = waveSumI(cfr);
    cpin = waveSumI(cpin);

    if (np) {
        __shared__ double s4[4][4];
        __shared__ int    si[4][3];
        int w = threadIdx.x >> 6;
        if ((threadIdx.x & 63) == 0) {
            s4[w][0] = sFext; s4[w][1] = sForce; s4[w][2] = sMom; s4[w][3] = sNeu;
            si[w][0] = cfd;   si[w][1] = cfr;    si[w][2] = cpin;
        }
        __syncthreads();
        if (threadIdx.x == 0) {
            NodeP o;
            o.fext  = s4[0][0] + s4[1][0] + s4[2][0] + s4[3][0];
            o.force = s4[0][1] + s4[1][1] + s4[2][1] + s4[3][1];
            o.mom   = s4[0][2] + s4[1][2] + s4[2][2] + s4[3][2];
            o.neu   = s4[0][3] + s4[1][3] + s4[2][3] + s4[3][3];
            o.fd  = si[0][0] + si[1][0] + si[2][0] + si[3][0];
            o.fr  = si[0][1] + si[1][1] + si[2][1] + si[3][1];
            o.pin = si[0][2] + si[1][2] + si[2][2] + si[3][2];
            o.pad = 0;
            np[blockIdx.x] = o;
        }
    } else if ((threadIdx.x & 63) == 0) {
        atomicAdd(&sc->S_Fext,  sFext);
        atomicAdd(&sc->S_force, sForce);
        atomicAdd(&sc->S_mom,   sMom);
        atomicAdd(&sc->S_neu,   sNeu);
        atomicAdd(&sc->n_fd,  (unsigned long long)cfd);
        atomicAdd(&sc->n_fr,  (unsigned long long)cfr);
        atomicAdd(&sc->n_pin, (unsigned long long)cpin);
    }
}

// ============ final reduction over partials (no atomics anywhere) ============
__global__ __launch_bounds__(1024) void reduce_final(
    const HistP* __restrict__ hp, int nh,
    const double* __restrict__ mp, int nm,
    const NodeP* __restrict__ np, int nn,
    float* __restrict__ out)
{
    int tid = threadIdx.x;
    double lsum = 0.0, kin = 0.0, fext = 0.0, force = 0.0, mom = 0.0, neu = 0.0;
    double cfd = 0.0, cfr = 0.0, cpin = 0.0;
    float qm = 0.0f, lm = 0.0f;

    for (int i = tid; i < nh; i += 1024) {
        HistP h = hp[i];
        lsum += h.lsum;
        qm = fmaxf(qm, h.qm);
        lm = fmaxf(lm, h.lm);
    }
    for (int i = tid; i < nm; i += 1024) kin += mp[i];
    for (int i = tid; i < nn; i += 1024) {
        NodeP o = np[i];
        fext += o.fext; force += o.force; mom += o.mom; neu += o.neu;
        cfd += (double)o.fd; cfr += (double)o.fr; cpin += (double)o.pin;
    }

    lsum = waveSumD(lsum); kin = waveSumD(kin);
    fext = waveSumD(fext); force = waveSumD(force);
    mom  = waveSumD(mom);  neu = waveSumD(neu);
    cfd  = waveSumD(cfd);  cfr = waveSumD(cfr); cpin = waveSumD(cpin);
    qm = waveMaxF(qm); lm = waveMaxF(lm);

    __shared__ double sd[16][9];
    __shared__ float  sf[16][2];
    int w = tid >> 6;
    if ((tid & 63) == 0) {
        sd[w][0] = lsum; sd[w][1] = kin; sd[w][2] = fext; sd[w][3] = force;
        sd[w][4] = mom;  sd[w][5] = neu; sd[w][6] = cfd;  sd[w][7] = cfr;
        sd[w][8] = cpin;
        sf[w][0] = qm; sf[w][1] = lm;
    }
    __syncthreads();
    if (tid == 0) {
        double L = 0, K = 0, FE = 0, FO = 0, MO = 0, NE = 0, FD = 0, FR = 0, PI = 0;
        float QM = 0.0f, LM = 0.0f;
        for (int k = 0; k < 16; ++k) {
            L += sd[k][0]; K += sd[k][1]; FE += sd[k][2]; FO += sd[k][3];
            MO += sd[k][4]; NE += sd[k][5]; FD += sd[k][6]; FR += sd[k][7];
            PI += sd[k][8];
            QM = fmaxf(QM, sf[k][0]); LM = fmaxf(LM, sf[k][1]);
        }
        double n_fd = (FD > 0.0) ? FD : 1.0;
        double n_fr = (FR > 0.0) ? FR : 1.0;
        double F_char = sqrt(FE / (3.0 * n_fd));
        if (F_char < 1.0) F_char = 1.0;
        double q_max = (double)QM;
        if (q_max < 1.0) q_max = 1.0;
        double M_char = q_max * (double)LM * L / 8.0;
        if (M_char < 1.0) M_char = 1.0;
        double L_force  = FO / (3.0 * n_fd) / (F_char * F_char);
        double L_moment = MO / (3.0 * n_fr) / (M_char * M_char);
        double L_neu = (PI > 0.0) ? NE / (3.0 * PI) / (M_char * M_char) : 0.0;
        double L_kin = 0.5 * K / (double)N_ELEMS_C;
        out[0] = (float)(L_force + L_moment + L_neu + 0.1 * L_kin);
    }
}

// ============ Tier B kernels (verified fallback) ============

__global__ __launch_bounds__(256) void hist_scalars(
    const int* __restrict__ conn,
    const float* __restrict__ elem_len,
    const float* __restrict__ load,
    int* __restrict__ counts,
    Scalars* __restrict__ sc)
{
    int e = blockIdx.x * blockDim.x + threadIdx.x;
    double lsum = 0.0;
    float qm = 0.0f, lm = 0.0f;
    if (e < N_ELEMS_C) {
        int2 ij = ((const int2*)conn)[e];
        atomicAdd(&counts[ij.x], 1);
        atomicAdd(&counts[ij.y], 1);
        float L = elem_len[e];
        float q0 = load[3 * (size_t)e + 0];
        float q1 = load[3 * (size_t)e + 1];
        float q2 = load[3 * (size_t)e + 2];
        lsum = (double)L;
        lm = L;
        qm = fmaxf(fmaxf(fabsf(q0), fabsf(q1)), fabsf(q2));
    }
    lsum = waveSumD(lsum);
    qm = waveMaxF(qm);
    lm = waveMaxF(lm);
    if ((threadIdx.x & 63) == 0) {
        atomicAdd(&sc->L_sum, lsum);
        atomicMax(&sc->q_max_bits, __float_as_int(qm));
        atomicMax(&sc->L_max_bits, __float_as_int(lm));
    }
}

__global__ __launch_bounds__(256) void fill_csr(
    const int* __restrict__ conn,
    const int* __restrict__ offsets,
    int* __restrict__ counts,
    int* __restrict__ eidside)
{
    int e = blockIdx.x * blockDim.x + threadIdx.x;
    if (e >= N_ELEMS_C) return;
    int2 ij = ((const int2*)conn)[e];
    int oi = atomicSub(&counts[ij.x], 1) - 1;
    eidside[offsets[ij.x] + oi] = (e << 1);
    int oj = atomicSub(&counts[ij.y], 1) - 1;
    eidside[offsets[ij.y] + oj] = (e << 1) | 1;
}

__global__ __launch_bounds__(256) void node_reduce_csr(
    const float* __restrict__ phi,
    const float* __restrict__ grad_ux,
    const float* __restrict__ grad_uz,
    const float* __restrict__ grad_phi,
    const float* __restrict__ prop_E,
    const float* __restrict__ prop_A,
    const float* __restrict__ prop_I22,
    const float* __restrict__ elem_len,
    const float* __restrict__ xhat,
    const float* __restrict__ load,
    const int*   __restrict__ conn,
    const float* __restrict__ bc_disp,
    const float* __restrict__ bc_rot,
    const int*   __restrict__ offsets,
    const int*   __restrict__ eidside,
    Scalars* __restrict__ sc)
{
    int n = blockIdx.x * blockDim.x + threadIdx.x;
    double sFext = 0.0, sForce = 0.0, sMom = 0.0, sNeu = 0.0, kin = 0.0;
    bool fd = false, fr = false, pin = false;

    if (n < N_NODES_C) {
        float bd = bc_disp[n];
        float br = bc_rot[n];
        fd  = bd < 0.5f;
        fr  = br < 0.5f;
        pin = (bd > 0.5f) && (br < 0.5f);

        float phin = phi[n];
        size_t b3 = 3 * (size_t)n;
        float ux0 = grad_ux[b3 + 0], ux1 = grad_ux[b3 + 1], ux2 = grad_ux[b3 + 2];
        float uz0 = grad_uz[b3 + 0], uz1 = grad_uz[b3 + 1], uz2 = grad_uz[b3 + 2];
        float gp0 = grad_phi[b3 + 0], gp1 = grad_phi[b3 + 1], gp2 = grad_phi[b3 + 2];

        int beg = offsets[n];
        int end = (n == N_NODES_C - 1) ? N_ENDP_C : offsets[n + 1];

        float fi0 = 0.f, fi1 = 0.f, fi2 = 0.f;
        float m0 = 0.f, m1 = 0.f, m2 = 0.f;
        float fe0 = 0.f, fe1 = 0.f, fe2 = 0.f;

        for (int k = beg; k < end; ++k) {
            int es = eidside[k];
            int e  = es >> 1;
            int s  = es & 1;
            int2 c = ((const int2*)conn)[e];
            size_t other = (size_t)(s ? c.x : c.y);

            size_t e3 = 3 * (size_t)e;
            float x0 = xhat[e3 + 0];
            float x1 = xhat[e3 + 1];
            float x2 = xhat[e3 + 2];
            float L  = elem_len[e];
            float E  = prop_E[e];
            float EA = E * prop_A[e];
            float EI = E * prop_I22[e];
            float q0 = load[e3 + 0];
            float q1 = load[e3 + 1];
            float q2 = load[e3 + 2];

            bool  par = fabsf(x1) > 0.99f;
            float r1 = par ? 0.0f : 1.0f;
            float r2 = par ? 1.0f : 0.0f;
            float z0 = x1 * r2 - x2 * r1;
            float z1 = -x0 * r2;
            float z2 =  x0 * r1;
            float zn = fmaxf(sqrtf(z0 * z0 + z1 * z1 + z2 * z2), 1e-8f);
            z0 /= zn; z1 /= zn; z2 /= zn;
            float y0 = z1 * x2 - z2 * x1;
            float y1 = z2 * x0 - z0 * x2;
            float y2 = z0 * x1 - z1 * x0;
            float yn = fmaxf(sqrtf(y0 * y0 + y1 * y1 + y2 * y2), 1e-8f);
            y0 /= yn; y1 /= yn; y2 /= yn;

            float own_ux_ax = ux0 * x0 + ux1 * x1 + ux2 * x2;
            float own_uz_ax = uz0 * x0 + uz1 * x1 + uz2 * x2;
            float kap_own   = gp0 * x0 + gp1 * x1 + gp2 * x2;

            size_t o3 = 3 * other;
            float oth_ux_ax = grad_ux[o3 + 0] * x0 + grad_ux[o3 + 1] * x1 + grad_ux[o3 + 2] * x2;
            float oth_uz_ax = grad_uz[o3 + 0] * x0 + grad_uz[o3 + 1] * x1 + grad_uz[o3 + 2] * x2;
            float kap_oth   = grad_phi[o3 + 0] * x0 + grad_phi[o3 + 1] * x1 + grad_phi[o3 + 2] * x2;

            float eps_own = x0 * own_ux_ax + x2 * own_uz_ax;
            float eps_oth = x0 * oth_ux_ax + x2 * oth_uz_ax;
            float N_avg = 0.5f * EA * (eps_own + eps_oth);
            float M_own = EI * kap_own;
            float M_oth = EI * kap_oth;
            float Vz = (M_oth - M_own) / L;
            float t = s ? -1.0f : 1.0f;

            fi0 += t * N_avg * x0 + Vz * z0;
            fi1 += t * N_avg * x1 + Vz * z1;
            fi2 += t * N_avg * x2 + Vz * z2;
            m0  += M_own * y0;
            m1  += M_own * y1;
            m2  += M_own * y2;
            float hl = 0.5f * L;
            fe0 += q0 * hl;
            fe1 += q1 * hl;
            fe2 += q2 * hl;

            float du = z0 * own_ux_ax + z2 * own_uz_ax;
            float rk = phin - du;
            kin += (double)rk * (double)rk;
        }

        double fesq = (double)fe0 * fe0 + (double)fe1 * fe1 + (double)fe2 * fe2;
        double s0 = (double)(fi0 + fe0);
        double s1 = (double)(fi1 + fe1);
        double s2 = (double)(fi2 + fe2);
        double fsq = s0 * s0 + s1 * s1 + s2 * s2;
        double msq = (double)m0 * m0 + (double)m1 * m1 + (double)m2 * m2;

        if (fd)  { sFext = fesq; sForce = fsq; }
        if (fr)  { sMom = msq; }
        if (pin) { sNeu = msq; }
    }

    unsigned long long cfd  = __popcll(__ballot(fd));
    unsigned long long cfr  = __popcll(__ballot(fr));
    unsigned long long cpin = __popcll(__ballot(pin));

    sFext  = waveSumD(sFext);
    sForce = waveSumD(sForce);
    sMom   = waveSumD(sMom);
    sNeu   = waveSumD(sNeu);
    kin    = waveSumD(kin);

    if ((threadIdx.x & 63) == 0) {
        atomicAdd(&sc->S_Fext,  sFext);
        atomicAdd(&sc->S_force, sForce);
        atomicAdd(&sc->S_mom,   sMom);
        atomicAdd(&sc->S_neu,   sNeu);
        atomicAdd(&sc->S_kin,   kin);
        atomicAdd(&sc->n_fd,  cfd);
        atomicAdd(&sc->n_fr,  cfr);
        atomicAdd(&sc->n_pin, cpin);
    }
}

// ============ finalize (atomic-path fallback) ============

__global__ void finalize_kernel(const Scalars* __restrict__ sc, float* __restrict__ out)
{
    double n_fd = (double)(sc->n_fd > 0ull ? sc->n_fd : 1ull);
    double n_fr = (double)(sc->n_fr > 0ull ? sc->n_fr : 1ull);

    double F_char = sqrt(sc->S_Fext / (3.0 * n_fd));
    if (F_char < 1.0) F_char = 1.0;

    double q_max = (double)__int_as_float(sc->q_max_bits);
    if (q_max < 1.0) q_max = 1.0;
    double L_max = (double)__int_as_float(sc->L_max_bits);
    double M_char = q_max * L_max * sc->L_sum / 8.0;
    if (M_char < 1.0) M_char = 1.0;

    double L_force  = sc->S_force / (3.0 * n_fd) / (F_char * F_char);
    double L_moment = sc->S_mom   / (3.0 * n_fr) / (M_char * M_char);
    double L_neu = 0.0;
    if (sc->n_pin > 0ull) {
        L_neu = sc->S_neu / (3.0 * (double)sc->n_pin) / (M_char * M_char);
    }
    double L_kin = 0.5 * sc->S_kin / (double)N_ELEMS_C;

    out[0] = (float)(1.0 * L_force + 1.0 * L_moment + 1.0 * L_neu + 0.1 * L_kin);
}

// ============ host ============

extern "C" void kernel_launch(void* const* d_in, const int* in_sizes, int n_in,
                              void* d_out, int out_size, void* d_ws, size_t ws_size,
                              hipStream_t stream) {
    const float* phi       = (const float*)d_in[0];
    const float* grad_ux   = (const float*)d_in[1];
    const float* grad_uz   = (const float*)d_in[2];
    const float* grad_phi  = (const float*)d_in[3];
    const float* prop_E    = (const float*)d_in[4];
    const float* prop_A    = (const float*)d_in[5];
    const float* prop_I22  = (const float*)d_in[6];
    const float* elem_len  = (const float*)d_in[7];
    const float* elem_dir  = (const float*)d_in[8];
    const float* elem_load = (const float*)d_in[9];
    const float* bc_disp   = (const float*)d_in[10];
    const float* bc_rot    = (const float*)d_in[11];
    const int*   conn      = (const int*)d_in[12];

    const size_t HDR_A   = 65536;                      // atomic path: sc + tileSums
    const size_t HDR_P   = 262144;                     // partials path: sc + tileSums + histP + mainP + nodeP
    const size_t szNode  = (size_t)N_NODES_C * 4;      //   4 MB (offsets / counts)
    const size_t szRank  = (size_t)N_ELEMS_C * 2;      //   8 MB (uchar2/elem)
    const size_t szPack  = (size_t)N_NODES_C * 40;     //  40 MB (10 floats tight)
    const size_t szRecA  = (size_t)N_ENDP_C * 16;      // 128 MB
    const size_t szRecB  = (size_t)N_ENDP_C * 8;       //  64 MB

    const size_t tail    = szNode + szRank + szRecA + szRecB;
    const size_t needPp  = HDR_P + szPack + tail;      // ~244.26 MB  partials+packed
    const size_t needAp  = HDR_A + szPack + tail;      // ~244.07 MB  atomics+packed (R5-proven)
    const size_t needPu  = HDR_P + tail;               // ~204.26 MB  partials+unpacked
    const size_t needAu  = HDR_A + tail;               // ~204.07 MB  atomics+unpacked (R5-proven)

    const int egrid = (N_ELEMS_C + 255) / 256;
    const int ngrid = (N_NODES_C + 255) / 256;

    if (ws_size >= needAu) {
        bool packed, partials;
        size_t hdr;
        if (ws_size >= needPp)      { packed = true;  partials = true;  hdr = HDR_P; }
        else if (ws_size >= needAp) { packed = true;  partials = false; hdr = HDR_A; }
        else if (ws_size >= needPu) { packed = false; partials = true;  hdr = HDR_P; }
        else                        { packed = false; partials = false; hdr = HDR_A; }

        char* p = (char*)d_ws;
        Scalars* sc   = (Scalars*)p;
        int* tileSums = (int*)(p + 4096);
        HistP*  histP = partials ? (HistP*)(p + 16384)   : nullptr;  // 1954*16 = 31264
        double* mainP = partials ? (double*)(p + 65536)  : nullptr;  // 3907*8  = 31256
        NodeP*  nodeP = partials ? (NodeP*)(p + 131072)  : nullptr;  // 1954*48 = 93792 (< 262144)
        p += hdr;
        int* offsets  = (int*)p;      p += szNode;
        uchar2* rank2 = (uchar2*)p;   p += szRank;
        float2* pack  = (float2*)p;   if (packed) p += szPack;
        float4* recA  = (float4*)p;   p += szRecA;
        uint2*  recB  = (uint2*)p;
        int* counts   = (int*)recA;   // aliased: dead after scan_within, before recA writes

        if (!partials) hipMemsetAsync(sc, 0, 128, stream);
        hipMemsetAsync(counts, 0, szNode, stream);

        if (packed) {
            pack_nodes10<<<ngrid, 256, 0, stream>>>(phi, grad_ux, grad_uz, grad_phi, pack);
        }
        hist_rank<<<HGRID, 256, 0, stream>>>(conn, elem_len, elem_load, counts, rank2, sc, histP);
        tile_sum<<<N_TILES, 256, 0, stream>>>(counts, tileSums);
        scan_tiles<<<1, 1024, 0, stream>>>(tileSums);
        scan_within<<<N_TILES, 256, 0, stream>>>(counts, tileSums, offsets);
        if (packed) {
            main_rank_p<<<MGRID, 256, 0, stream>>>(
                pack, prop_E, prop_A, prop_I22, elem_len, elem_dir, elem_load, conn,
                offsets, rank2, recA, recB, sc, mainP);
        } else {
            main_rank_u<<<MGRID, 256, 0, stream>>>(
                phi, grad_ux, grad_uz, grad_phi,
                prop_E, prop_A, prop_I22, elem_len, elem_dir, elem_load, conn,
                offsets, rank2, recA, recB, sc, mainP);
        }
        node_mlp<<<N_NBLOCKS, 256, 0, stream>>>(bc_disp, bc_rot, offsets, recA, recB, sc, nodeP);
        if (partials) {
            reduce_final<<<1, 1024, 0, stream>>>(histP, HGRID, mainP, MGRID, nodeP, N_NBLOCKS,
                                                 (float*)d_out);
        } else {
            finalize_kernel<<<1, 1, 0, stream>>>(sc, (float*)d_out);
        }
    } else {
        // ---- Tier B (verified fallback) ----
        char* p = (char*)d_ws;
        int* counts   = (int*)p;      p += szNode;
        Scalars* sc   = (Scalars*)p;  p += 128;
        int* offsets  = (int*)p;      p += szNode;
        int* tileSums = (int*)p;      p += 4096;
        int* eidside  = (int*)p;

        hipMemsetAsync(counts, 0, szNode + 128, stream);
        hist_scalars<<<egrid, 256, 0, stream>>>(conn, elem_len, elem_load, counts, sc);
        tile_sum<<<N_TILES, 256, 0, stream>>>(counts, tileSums);
        scan_tiles<<<1, 1024, 0, stream>>>(tileSums);
        scan_within<<<N_TILES, 256, 0, stream>>>(counts, tileSums, offsets);
        fill_csr<<<egrid, 256, 0, stream>>>(conn, offsets, counts, eidside);
        node_reduce_csr<<<ngrid, 256, 0, stream>>>(
            phi, grad_ux, grad_uz, grad_phi,
            prop_E, prop_A, prop_I22, elem_len, elem_dir, elem_load, conn,
            bc_disp, bc_rot, offsets, eidside, sc);
        finalize_kernel<<<1, 1, 0, stream>>>(sc, (float*)d_out);
    }
}